// Round 1
// baseline (2228.835 us; speedup 1.0000x reference)
//
#include <hip/hip_runtime.h>
#include <hip/hip_bf16.h>
#include <math.h>

#define CDIM 512
#define NTOK 3136
#define BATCH 8
#define MTOT (BATCH*NTOK)   // 25088
#define NHEAD 8
#define DHEAD 64
#define HW 56

// ---------------- prep: per-channel inv_scale and power ----------------
__global__ void prep_kernel(const float* __restrict__ scale_p,
                            const float* __restrict__ power_p,
                            float* __restrict__ inv_scale,
                            float* __restrict__ power) {
    int c = threadIdx.x;
    if (c < CDIM) {
        float s = log1pf(expf(scale_p[c]));        // softplus
        inv_scale[c] = 1.0f / s;
        power[c] = 1.0f + 4.0f / (1.0f + expf(-power_p[c]));  // 1+ALPHA*sigmoid
    }
}

// ---------------- generic K=512 GEMM: out[m,o] = sum_c A[m,c]*Wt[o,c] ----------------
// EPI 0: qg -> out0=Q (o<512), out1=G (o>=512)
// EPI 1: kv -> out0=K = (acc+pos_enc)*inv_scale (o<512), out1=V (o>=512); aux0=pos_enc, aux1=inv_scale
// EPI 2: proj -> out0 = acc + proj_b; aux0=proj_b
template<int EPI>
__global__ __launch_bounds__(256) void gemm_k512(
    const float* __restrict__ A,
    const float* __restrict__ Wt,
    float* __restrict__ out0,
    float* __restrict__ out1,
    const float* __restrict__ aux0,
    const float* __restrict__ aux1)
{
    __shared__ float As[16][132];
    __shared__ float Bs[16][132];
    const int tid = threadIdx.x;
    const int m0 = blockIdx.x * 128;
    const int o0 = blockIdx.y * 128;
    const int tx = tid & 15;
    const int ty = tid >> 4;
    float acc[8][8];
    #pragma unroll
    for (int i = 0; i < 8; ++i)
        #pragma unroll
        for (int j = 0; j < 8; ++j) acc[i][j] = 0.f;

    for (int k0 = 0; k0 < 512; k0 += 16) {
        #pragma unroll
        for (int i = 0; i < 2; ++i) {
            int f = tid + i * 256;     // 0..511
            int r = f >> 2;            // 0..127
            int kq = f & 3;            // 0..3
            float4 av = *(const float4*)(A + (size_t)(m0 + r) * CDIM + k0 + kq * 4);
            As[kq*4+0][r] = av.x; As[kq*4+1][r] = av.y; As[kq*4+2][r] = av.z; As[kq*4+3][r] = av.w;
            float4 bv = *(const float4*)(Wt + (size_t)(o0 + r) * CDIM + k0 + kq * 4);
            Bs[kq*4+0][r] = bv.x; Bs[kq*4+1][r] = bv.y; Bs[kq*4+2][r] = bv.z; Bs[kq*4+3][r] = bv.w;
        }
        __syncthreads();
        #pragma unroll
        for (int kk = 0; kk < 16; ++kk) {
            float4 a0 = *(const float4*)&As[kk][ty*8];
            float4 a1 = *(const float4*)&As[kk][ty*8+4];
            float4 b0 = *(const float4*)&Bs[kk][tx*8];
            float4 b1 = *(const float4*)&Bs[kk][tx*8+4];
            float av[8]  = {a0.x,a0.y,a0.z,a0.w,a1.x,a1.y,a1.z,a1.w};
            float bvv[8] = {b0.x,b0.y,b0.z,b0.w,b1.x,b1.y,b1.z,b1.w};
            #pragma unroll
            for (int i = 0; i < 8; ++i)
                #pragma unroll
                for (int j = 0; j < 8; ++j)
                    acc[i][j] = fmaf(av[i], bvv[j], acc[i][j]);
        }
        __syncthreads();
    }
    #pragma unroll
    for (int i = 0; i < 8; ++i) {
        int m = m0 + ty*8 + i;
        size_t mrow = (size_t)m * CDIM;
        #pragma unroll
        for (int jj = 0; jj < 2; ++jj) {
            int o = o0 + tx*8 + jj*4;
            float4 v4 = make_float4(acc[i][jj*4+0], acc[i][jj*4+1], acc[i][jj*4+2], acc[i][jj*4+3]);
            if (EPI == 0) {
                if (o < CDIM) *(float4*)(out0 + mrow + o) = v4;
                else          *(float4*)(out1 + mrow + (o - CDIM)) = v4;
            } else if (EPI == 1) {
                if (o < CDIM) {
                    int n = m % NTOK;
                    float4 pv = *(const float4*)(aux0 + (size_t)n * CDIM + o);
                    float4 is = *(const float4*)(aux1 + o);
                    v4.x = (v4.x + pv.x) * is.x;
                    v4.y = (v4.y + pv.y) * is.y;
                    v4.z = (v4.z + pv.z) * is.z;
                    v4.w = (v4.w + pv.w) * is.w;
                    *(float4*)(out0 + mrow + o) = v4;
                } else {
                    *(float4*)(out1 + mrow + (o - CDIM)) = v4;
                }
            } else {
                float4 pb = *(const float4*)(aux0 + o);
                v4.x += pb.x; v4.y += pb.y; v4.z += pb.z; v4.w += pb.w;
                *(float4*)(out0 + mrow + o) = v4;
            }
        }
    }
}

// ---------------- depthwise 3x3 conv on Q (NHWC), zero pad 1 ----------------
__global__ __launch_bounds__(256) void conv3_kernel(const float* __restrict__ Q,
                                                    const float* __restrict__ enh_w,
                                                    float* __restrict__ QE) {
    int gid = blockIdx.x * 256 + threadIdx.x;
    int c = gid & (CDIM - 1);
    int m = gid >> 9;
    int b = m / NTOK;
    int nsp = m - b * NTOK;
    int y = nsp / HW, x = nsp - y * HW;
    float acc = 0.f;
    #pragma unroll
    for (int dy = 0; dy < 3; ++dy) {
        int yy = y + dy - 1;
        if (yy < 0 || yy >= HW) continue;
        #pragma unroll
        for (int dx = 0; dx < 3; ++dx) {
            int xx = x + dx - 1;
            if (xx < 0 || xx >= HW) continue;
            acc = fmaf(Q[((size_t)(b * NTOK + yy * HW + xx)) * CDIM + c],
                       enh_w[c * 9 + dy * 3 + dx], acc);
        }
    }
    QE[gid] = acc;
}

// ---------------- per-channel BN stats (sum, sumsq) ----------------
__global__ __launch_bounds__(256) void stats_kernel(const float* __restrict__ QE,
                                                    float* __restrict__ ssum,
                                                    float* __restrict__ ssq) {
    int c0 = threadIdx.x;              // 0..255
    int rowStart = blockIdx.x * 64;    // 392 blocks * 64 rows
    float s1a = 0, s2a = 0, s1b = 0, s2b = 0;
    for (int r = 0; r < 64; ++r) {
        size_t base = (size_t)(rowStart + r) * CDIM;
        float va = QE[base + c0];
        float vb = QE[base + c0 + 256];
        s1a += va; s2a += va * va;
        s1b += vb; s2b += vb * vb;
    }
    atomicAdd(&ssum[c0], s1a);       atomicAdd(&ssq[c0], s2a);
    atomicAdd(&ssum[c0 + 256], s1b); atomicAdd(&ssq[c0 + 256], s2b);
}

__global__ void bnprep_kernel(const float* __restrict__ ssum, const float* __restrict__ ssq,
                              const float* __restrict__ bn_g, const float* __restrict__ bn_b,
                              float* __restrict__ achan, float* __restrict__ bchan) {
    int c = threadIdx.x;
    if (c < CDIM) {
        const float invM = 1.0f / (float)MTOT;
        float mean = ssum[c] * invM;
        float var  = ssq[c] * invM - mean * mean;
        float a = bn_g[c] * rsqrtf(var + 1e-5f);
        achan[c] = a;
        bchan[c] = bn_b[c] - mean * a;
    }
}

// ---------------- finalize q: Q = (Q + ew*relu(a*QE+b)) * inv_scale ----------------
__global__ __launch_bounds__(256) void qfin_kernel(float* __restrict__ Q,
                                                   const float* __restrict__ QE,
                                                   const float* __restrict__ achan,
                                                   const float* __restrict__ bchan,
                                                   const float* __restrict__ inv_scale,
                                                   const float* __restrict__ ewp) {
    int gid = blockIdx.x * 256 + threadIdx.x;
    int c = gid & (CDIM - 1);
    float ew = ewp[0];
    float e = fmaxf(fmaf(achan[c], QE[gid], bchan[c]), 0.f);
    Q[gid] = fmaf(ew, e, Q[gid]) * inv_scale[c];
}

// ---------------- kv reduction: kvmat[bh,128,64] = sum_n kf^T v * inv_n; kmean ----------------
__global__ __launch_bounds__(256) void kvred_kernel(const float* __restrict__ K,
                                                    const float* __restrict__ V,
                                                    const float* __restrict__ power,
                                                    float* __restrict__ kvmat,
                                                    float* __restrict__ kmean) {
    int bh = blockIdx.x;          // 0..63
    int b = bh >> 3, head = bh & 7;
    int chunk = blockIdx.y;       // 0..7 (392 rows each)
    int tid = threadIdx.x;
    int dd = tid & 127;           // 0..127 kf-dim
    int eh = tid >> 7;            // 0..1 (e block of 32)
    __shared__ float ks[2][64], vs[2][64];
    float acc[32];
    #pragma unroll
    for (int e = 0; e < 32; ++e) acc[e] = 0.f;
    float ksum = 0.f;
    int dch = dd & 63;
    float p = power[head * 64 + dch];
    bool negside = dd >= 64;

    int nEnd = chunk * 392 + 392;
    for (int n0 = chunk * 392; n0 < nEnd; n0 += 2) {
        {
            int which = (tid >> 6) & 1;   // 0:k 1:v
            int row = tid >> 7;           // 0 or 1
            int lane = tid & 63;
            size_t rowb = ((size_t)(b * NTOK + n0 + row)) * CDIM + head * 64 + lane;
            if (which == 0) ks[row][lane] = K[rowb];
            else            vs[row][lane] = V[rowb];
        }
        __syncthreads();
        #pragma unroll
        for (int rr = 0; rr < 2; ++rr) {
            float kraw = ks[rr][dch];
            float kx = negside ? -kraw : kraw;
            float kf = kx > 0.f ? __powf(kx, p) : 0.f;
            ksum += kf;
            #pragma unroll
            for (int e = 0; e < 32; ++e)
                acc[e] = fmaf(kf, vs[rr][eh * 32 + e], acc[e]);
        }
        __syncthreads();
    }
    const float inv_n = 1.0f / (float)NTOK;
    float* kvdst = kvmat + (size_t)bh * 8192 + dd * 64 + eh * 32;
    #pragma unroll
    for (int e = 0; e < 32; ++e) atomicAdd(&kvdst[e], acc[e] * inv_n);
    if (eh == 0) atomicAdd(&kmean[bh * 128 + dd], ksum * inv_n);
}

// ---------------- attention apply: one wave per token ----------------
__global__ __launch_bounds__(256) void attn_kernel(const float* __restrict__ Q,
                                                   const float* __restrict__ kvmat,
                                                   const float* __restrict__ kmean,
                                                   const float* __restrict__ power,
                                                   float* __restrict__ ATT) {
    int bh = blockIdx.x;          // 0..63
    int b = bh >> 3, head = bh & 7;
    int tchunk = blockIdx.y;      // 0..48, 64 tokens each
    int tid = threadIdx.x;
    int wave = tid >> 6, lane = tid & 63;
    __shared__ float kv_s[8192];
    __shared__ float km_s[128];
    for (int i = tid; i < 8192; i += 256) kv_s[i] = kvmat[(size_t)bh * 8192 + i];
    if (tid < 128) km_s[tid] = kmean[bh * 128 + tid];
    __syncthreads();

    float p = power[head * 64 + lane];
    bool sim_side = lane < 32;

    for (int t = 0; t < 16; ++t) {
        int n = tchunk * 64 + wave * 16 + t;
        size_t qb = ((size_t)(b * NTOK + n)) * CDIM + head * 64;
        float qv = Q[qb + lane];
        float ax = fabsf(qv);
        float tp = ax > 0.f ? __powf(ax, p) : 0.f;
        float qpos = qv > 0.f ? tp : 0.f;
        float qneg = qv < 0.f ? tp : 0.f;
        // z denominators (all-lane butterfly reduce)
        float s_sim = qpos * km_s[lane] + qneg * km_s[64 + lane];
        float s_opp = qneg * km_s[lane] + qpos * km_s[64 + lane];
        #pragma unroll
        for (int off = 32; off > 0; off >>= 1) {
            s_sim += __shfl_xor(s_sim, off);
            s_opp += __shfl_xor(s_opp, off);
        }
        float z  = 1.f / (s_sim + 1e-6f);
        float z2 = 1.f / (s_opp + 1e-6f);
        float accum = 0.f;
        #pragma unroll 8
        for (int j = 0; j < 64; ++j) {
            float qp = __shfl(qpos, j);
            float qn = __shfl(qneg, j);
            float a  = sim_side ? qp : qn;
            float bq = sim_side ? qn : qp;
            accum = fmaf(a, kv_s[j * 64 + lane], fmaf(bq, kv_s[(64 + j) * 64 + lane], accum));
        }
        accum *= sim_side ? z : z2;
        ATT[qb + lane] = accum;
    }
}

// ---------------- v 5x5 depthwise conv + gate: PRE = (ATT + conv(V)+bias) * G ----------------
__global__ __launch_bounds__(256) void voutg_kernel(const float* __restrict__ V,
                                                    const float* __restrict__ ATT,
                                                    const float* __restrict__ G,
                                                    const float* __restrict__ dwc_w,
                                                    const float* __restrict__ dwc_b,
                                                    float* __restrict__ PRE) {
    int gid = blockIdx.x * 256 + threadIdx.x;
    int c = gid & (CDIM - 1);
    int m = gid >> 9;
    int dch = c & 63;
    int b = m / NTOK;
    int nsp = m - b * NTOK;
    int y = nsp / HW, x = nsp - y * HW;
    float acc = dwc_b[dch];
    #pragma unroll
    for (int dy = 0; dy < 5; ++dy) {
        int yy = y + dy - 2;
        if (yy < 0 || yy >= HW) continue;
        #pragma unroll
        for (int dx = 0; dx < 5; ++dx) {
            int xx = x + dx - 2;
            if (xx < 0 || xx >= HW) continue;
            acc = fmaf(V[((size_t)(b * NTOK + yy * HW + xx)) * CDIM + c],
                       dwc_w[dch * 25 + dy * 5 + dx], acc);
        }
    }
    PRE[gid] = (ATT[gid] + acc) * G[gid];
}

extern "C" void kernel_launch(void* const* d_in, const int* in_sizes, int n_in,
                              void* d_out, int out_size, void* d_ws, size_t ws_size,
                              hipStream_t stream) {
    const float* x      = (const float*)d_in[0];
    const float* qg_w   = (const float*)d_in[1];
    const float* kv_w   = (const float*)d_in[2];
    const float* proj_w = (const float*)d_in[3];
    const float* proj_b = (const float*)d_in[4];
    const float* dwc_w  = (const float*)d_in[5];
    const float* dwc_b  = (const float*)d_in[6];
    const float* power_p= (const float*)d_in[7];
    const float* scale_p= (const float*)d_in[8];
    const float* enh_w  = (const float*)d_in[9];
    const float* bn_g   = (const float*)d_in[10];
    const float* bn_b   = (const float*)d_in[11];
    const float* ew_p   = (const float*)d_in[12];
    const float* pos    = (const float*)d_in[13];

    const size_t NELEM = (size_t)MTOT * CDIM;   // 12,845,056
    float* ws    = (float*)d_ws;
    float* Qb    = ws;
    float* Gb    = ws + NELEM;
    float* Kb    = ws + 2 * NELEM;
    float* Vb    = ws + 3 * NELEM;
    float* QEb   = ws + 4 * NELEM;      // reused as ATT
    float* SMALL = ws + 5 * NELEM;
    float* ssum  = SMALL;               // 512
    float* ssq   = SMALL + 512;         // 512
    float* kmean = SMALL + 1024;        // 8192
    float* kvmat = SMALL + 9216;        // 524288
    float* invs  = SMALL + 533504;      // 512
    float* powr  = SMALL + 534016;      // 512
    float* achan = SMALL + 534528;      // 512
    float* bchan = SMALL + 535040;      // 512
    float* ATTb  = QEb;                 // reuse (QE dead after qfin)
    float* PREb  = Kb;                  // reuse (K dead after kvred)

    // zero the accumulated small region (ssum,ssq,kmean,kvmat)
    hipMemsetAsync(SMALL, 0, (size_t)533504 * sizeof(float), stream);

    prep_kernel<<<1, 512, 0, stream>>>(scale_p, power_p, invs, powr);

    dim3 ggrid(196, 8);
    gemm_k512<0><<<ggrid, 256, 0, stream>>>(x, qg_w, Qb, Gb, nullptr, nullptr);
    gemm_k512<1><<<ggrid, 256, 0, stream>>>(x, kv_w, Kb, Vb, pos, invs);

    conv3_kernel<<<50176, 256, 0, stream>>>(Qb, enh_w, QEb);
    stats_kernel<<<392, 256, 0, stream>>>(QEb, ssum, ssq);
    bnprep_kernel<<<1, 512, 0, stream>>>(ssum, ssq, bn_g, bn_b, achan, bchan);
    qfin_kernel<<<50176, 256, 0, stream>>>(Qb, QEb, achan, bchan, invs, ew_p);

    kvred_kernel<<<dim3(64, 8), 256, 0, stream>>>(Kb, Vb, powr, kvmat, kmean);
    attn_kernel<<<dim3(64, 49), 256, 0, stream>>>(Qb, kvmat, kmean, powr, ATTb);

    voutg_kernel<<<50176, 256, 0, stream>>>(Vb, ATTb, Gb, dwc_w, dwc_b, PREb);

    dim3 pgrid(196, 4);
    gemm_k512<2><<<pgrid, 256, 0, stream>>>(PREb, proj_w, (float*)d_out, nullptr, proj_b, nullptr);
}

// Round 2
// 1915.037 us; speedup vs baseline: 1.1639x; 1.1639x over previous
//
#include <hip/hip_runtime.h>
#include <hip/hip_bf16.h>
#include <math.h>

#define CDIM 512
#define NTOK 3136
#define BATCH 8
#define MTOT (BATCH*NTOK)   // 25088
#define NHEAD 8
#define DHEAD 64
#define HW 56

// ---------------- prep: per-channel inv_scale and power ----------------
__global__ void prep_kernel(const float* __restrict__ scale_p,
                            const float* __restrict__ power_p,
                            float* __restrict__ inv_scale,
                            float* __restrict__ power) {
    int c = threadIdx.x;
    if (c < CDIM) {
        float s = log1pf(expf(scale_p[c]));        // softplus
        inv_scale[c] = 1.0f / s;
        power[c] = 1.0f + 4.0f / (1.0f + expf(-power_p[c]));  // 1+ALPHA*sigmoid
    }
}

// ---------------- generic K=512 GEMM: out[m,o] = sum_c A[m,c]*Wt[o,c] ----------------
template<int EPI>
__global__ __launch_bounds__(256) void gemm_k512(
    const float* __restrict__ A,
    const float* __restrict__ Wt,
    float* __restrict__ out0,
    float* __restrict__ out1,
    const float* __restrict__ aux0,
    const float* __restrict__ aux1)
{
    __shared__ float As[16][132];
    __shared__ float Bs[16][132];
    const int tid = threadIdx.x;
    const int m0 = blockIdx.x * 128;
    const int o0 = blockIdx.y * 128;
    const int tx = tid & 15;
    const int ty = tid >> 4;
    float acc[8][8];
    #pragma unroll
    for (int i = 0; i < 8; ++i)
        #pragma unroll
        for (int j = 0; j < 8; ++j) acc[i][j] = 0.f;

    for (int k0 = 0; k0 < 512; k0 += 16) {
        #pragma unroll
        for (int i = 0; i < 2; ++i) {
            int f = tid + i * 256;     // 0..511
            int r = f >> 2;            // 0..127
            int kq = f & 3;            // 0..3
            float4 av = *(const float4*)(A + (size_t)(m0 + r) * CDIM + k0 + kq * 4);
            As[kq*4+0][r] = av.x; As[kq*4+1][r] = av.y; As[kq*4+2][r] = av.z; As[kq*4+3][r] = av.w;
            float4 bv = *(const float4*)(Wt + (size_t)(o0 + r) * CDIM + k0 + kq * 4);
            Bs[kq*4+0][r] = bv.x; Bs[kq*4+1][r] = bv.y; Bs[kq*4+2][r] = bv.z; Bs[kq*4+3][r] = bv.w;
        }
        __syncthreads();
        #pragma unroll
        for (int kk = 0; kk < 16; ++kk) {
            float4 a0 = *(const float4*)&As[kk][ty*8];
            float4 a1 = *(const float4*)&As[kk][ty*8+4];
            float4 b0 = *(const float4*)&Bs[kk][tx*8];
            float4 b1 = *(const float4*)&Bs[kk][tx*8+4];
            float av[8]  = {a0.x,a0.y,a0.z,a0.w,a1.x,a1.y,a1.z,a1.w};
            float bvv[8] = {b0.x,b0.y,b0.z,b0.w,b1.x,b1.y,b1.z,b1.w};
            #pragma unroll
            for (int i = 0; i < 8; ++i)
                #pragma unroll
                for (int j = 0; j < 8; ++j)
                    acc[i][j] = fmaf(av[i], bvv[j], acc[i][j]);
        }
        __syncthreads();
    }
    #pragma unroll
    for (int i = 0; i < 8; ++i) {
        int m = m0 + ty*8 + i;
        size_t mrow = (size_t)m * CDIM;
        #pragma unroll
        for (int jj = 0; jj < 2; ++jj) {
            int o = o0 + tx*8 + jj*4;
            float4 v4 = make_float4(acc[i][jj*4+0], acc[i][jj*4+1], acc[i][jj*4+2], acc[i][jj*4+3]);
            if (EPI == 0) {
                if (o < CDIM) *(float4*)(out0 + mrow + o) = v4;
                else          *(float4*)(out1 + mrow + (o - CDIM)) = v4;
            } else if (EPI == 1) {
                if (o < CDIM) {
                    int n = m % NTOK;
                    float4 pv = *(const float4*)(aux0 + (size_t)n * CDIM + o);
                    float4 is = *(const float4*)(aux1 + o);
                    v4.x = (v4.x + pv.x) * is.x;
                    v4.y = (v4.y + pv.y) * is.y;
                    v4.z = (v4.z + pv.z) * is.z;
                    v4.w = (v4.w + pv.w) * is.w;
                    *(float4*)(out0 + mrow + o) = v4;
                } else {
                    *(float4*)(out1 + mrow + (o - CDIM)) = v4;
                }
            } else {
                float4 pb = *(const float4*)(aux0 + o);
                v4.x += pb.x; v4.y += pb.y; v4.z += pb.z; v4.w += pb.w;
                *(float4*)(out0 + mrow + o) = v4;
            }
        }
    }
}

// ---------------- depthwise 3x3 conv on Q (NHWC), zero pad 1 ----------------
__global__ __launch_bounds__(256) void conv3_kernel(const float* __restrict__ Q,
                                                    const float* __restrict__ enh_w,
                                                    float* __restrict__ QE) {
    int gid = blockIdx.x * 256 + threadIdx.x;
    int c = gid & (CDIM - 1);
    int m = gid >> 9;
    int b = m / NTOK;
    int nsp = m - b * NTOK;
    int y = nsp / HW, x = nsp - y * HW;
    float acc = 0.f;
    #pragma unroll
    for (int dy = 0; dy < 3; ++dy) {
        int yy = y + dy - 1;
        if (yy < 0 || yy >= HW) continue;
        #pragma unroll
        for (int dx = 0; dx < 3; ++dx) {
            int xx = x + dx - 1;
            if (xx < 0 || xx >= HW) continue;
            acc = fmaf(Q[((size_t)(b * NTOK + yy * HW + xx)) * CDIM + c],
                       enh_w[c * 9 + dy * 3 + dx], acc);
        }
    }
    QE[gid] = acc;
}

// ---------------- per-channel BN stats (sum, sumsq) ----------------
__global__ __launch_bounds__(256) void stats_kernel(const float* __restrict__ QE,
                                                    float* __restrict__ ssum,
                                                    float* __restrict__ ssq) {
    int c0 = threadIdx.x;              // 0..255
    int rowStart = blockIdx.x * 64;    // 392 blocks * 64 rows
    float s1a = 0, s2a = 0, s1b = 0, s2b = 0;
    for (int r = 0; r < 64; ++r) {
        size_t base = (size_t)(rowStart + r) * CDIM;
        float va = QE[base + c0];
        float vb = QE[base + c0 + 256];
        s1a += va; s2a += va * va;
        s1b += vb; s2b += vb * vb;
    }
    atomicAdd(&ssum[c0], s1a);       atomicAdd(&ssq[c0], s2a);
    atomicAdd(&ssum[c0 + 256], s1b); atomicAdd(&ssq[c0 + 256], s2b);
}

__global__ void bnprep_kernel(const float* __restrict__ ssum, const float* __restrict__ ssq,
                              const float* __restrict__ bn_g, const float* __restrict__ bn_b,
                              float* __restrict__ achan, float* __restrict__ bchan) {
    int c = threadIdx.x;
    if (c < CDIM) {
        const float invM = 1.0f / (float)MTOT;
        float mean = ssum[c] * invM;
        float var  = ssq[c] * invM - mean * mean;
        float a = bn_g[c] * rsqrtf(var + 1e-5f);
        achan[c] = a;
        bchan[c] = bn_b[c] - mean * a;
    }
}

// ---------------- finalize q: Q = (Q + ew*relu(a*QE+b)) * inv_scale ----------------
__global__ __launch_bounds__(256) void qfin_kernel(float* __restrict__ Q,
                                                   const float* __restrict__ QE,
                                                   const float* __restrict__ achan,
                                                   const float* __restrict__ bchan,
                                                   const float* __restrict__ inv_scale,
                                                   const float* __restrict__ ewp) {
    int gid = blockIdx.x * 256 + threadIdx.x;
    int c = gid & (CDIM - 1);
    float ew = ewp[0];
    float e = fmaxf(fmaf(achan[c], QE[gid], bchan[c]), 0.f);
    Q[gid] = fmaf(ew, e, Q[gid]) * inv_scale[c];
}

// ---------------- kvred v2: tiled LDS, KF computed once, partial outputs ----------------
// grid (64 bh, 14 chunks); each block: 224 rows in 7 tiles of 32.
// Outputs: PKV[(chunk*64+bh)][128][64] raw sums; PKM[(chunk*64+bh)][128] raw kf col sums.
__global__ __launch_bounds__(256) void kvred2_kernel(const float* __restrict__ K,
                                                     const float* __restrict__ V,
                                                     const float* __restrict__ power,
                                                     float* __restrict__ PKV,
                                                     float* __restrict__ PKM) {
    int bh = blockIdx.x;
    int b = bh >> 3, head = bh & 7;
    int chunk = blockIdx.y;       // 0..13
    int t = threadIdx.x;
    __shared__ float Ks[32][64];
    __shared__ float Vs[32][64];
    __shared__ float KFs[32][128];

    // KF-compute role: fixed d for this thread
    const int dkf = t & 127;
    const float p_kf = power[head * 64 + (dkf & 63)];
    const bool neg_kf = dkf >= 64;
    const int rbase = t >> 7;     // 0 or 1

    // FMA role: 4 d x 8 e
    const int d0 = (t >> 3) * 4;
    const int e0 = (t & 7) * 8;
    float acc[4][8];
    #pragma unroll
    for (int i = 0; i < 4; ++i)
        #pragma unroll
        for (int j = 0; j < 8; ++j) acc[i][j] = 0.f;
    float kmsum = 0.f;            // threads t<128: column t of KF

    const int nbase = b * NTOK + chunk * 224;
    for (int tile = 0; tile < 7; ++tile) {
        int n0 = nbase + tile * 32;
        #pragma unroll
        for (int i = 0; i < 2; ++i) {
            int f = t + i * 256;          // 0..511
            int row = f >> 4, c4 = (f & 15) * 4;
            size_t g = (size_t)(n0 + row) * CDIM + head * 64 + c4;
            *(float4*)&Ks[row][c4] = *(const float4*)(K + g);
            *(float4*)&Vs[row][c4] = *(const float4*)(V + g);
        }
        __syncthreads();
        #pragma unroll
        for (int kk = 0; kk < 16; ++kk) {
            int row = 2 * kk + rbase;
            float kraw = Ks[row][dkf & 63];
            float kx = neg_kf ? -kraw : kraw;
            KFs[row][dkf] = kx > 0.f ? __powf(kx, p_kf) : 0.f;
        }
        __syncthreads();
        if (t < 128) {
            #pragma unroll
            for (int r = 0; r < 32; ++r) kmsum += KFs[r][t];
        }
        #pragma unroll
        for (int r = 0; r < 32; ++r) {
            float4 kf4 = *(const float4*)&KFs[r][d0];
            float4 va  = *(const float4*)&Vs[r][e0];
            float4 vb  = *(const float4*)&Vs[r][e0 + 4];
            float kk4[4] = {kf4.x, kf4.y, kf4.z, kf4.w};
            float vv[8]  = {va.x, va.y, va.z, va.w, vb.x, vb.y, vb.z, vb.w};
            #pragma unroll
            for (int i = 0; i < 4; ++i)
                #pragma unroll
                for (int j = 0; j < 8; ++j)
                    acc[i][j] = fmaf(kk4[i], vv[j], acc[i][j]);
        }
        __syncthreads();
    }
    size_t base = ((size_t)(chunk * 64 + bh)) * 8192;
    #pragma unroll
    for (int i = 0; i < 4; ++i) {
        *(float4*)(PKV + base + (size_t)(d0 + i) * 64 + e0)     = make_float4(acc[i][0], acc[i][1], acc[i][2], acc[i][3]);
        *(float4*)(PKV + base + (size_t)(d0 + i) * 64 + e0 + 4) = make_float4(acc[i][4], acc[i][5], acc[i][6], acc[i][7]);
    }
    if (t < 128) PKM[(chunk * 64 + bh) * 128 + t] = kmsum;
}

// reduce partials: kvmat[bh][128][64], kmean[bh][128]
__global__ __launch_bounds__(256) void kvreduce_kernel(const float* __restrict__ PKV,
                                                       const float* __restrict__ PKM,
                                                       float* __restrict__ kvmat,
                                                       float* __restrict__ kmean) {
    int gid = blockIdx.x * 256 + threadIdx.x;   // 0..532479
    const float inv_n = 1.0f / (float)NTOK;
    if (gid < 524288) {
        float s = 0.f;
        #pragma unroll
        for (int c = 0; c < 14; ++c) s += PKV[(size_t)c * 524288 + gid];
        kvmat[gid] = s * inv_n;
    } else {
        int j = gid - 524288;                   // 0..8191
        float s = 0.f;
        #pragma unroll
        for (int c = 0; c < 14; ++c) s += PKM[c * 8192 + j];
        kmean[j] = s * inv_n;
    }
}

// ---------------- attention apply: one wave per token ----------------
__global__ __launch_bounds__(256) void attn_kernel(const float* __restrict__ Q,
                                                   const float* __restrict__ kvmat,
                                                   const float* __restrict__ kmean,
                                                   const float* __restrict__ power,
                                                   float* __restrict__ ATT) {
    int bh = blockIdx.x;          // 0..63
    int b = bh >> 3, head = bh & 7;
    int tchunk = blockIdx.y;      // 0..48, 64 tokens each
    int tid = threadIdx.x;
    int wave = tid >> 6, lane = tid & 63;
    __shared__ float kv_s[8192];
    __shared__ float km_s[128];
    for (int i = tid; i < 8192; i += 256) kv_s[i] = kvmat[(size_t)bh * 8192 + i];
    if (tid < 128) km_s[tid] = kmean[bh * 128 + tid];
    __syncthreads();

    float p = power[head * 64 + lane];
    bool sim_side = lane < 32;

    for (int t = 0; t < 16; ++t) {
        int n = tchunk * 64 + wave * 16 + t;
        size_t qb = ((size_t)(b * NTOK + n)) * CDIM + head * 64;
        float qv = Q[qb + lane];
        float ax = fabsf(qv);
        float tp = ax > 0.f ? __powf(ax, p) : 0.f;
        float qpos = qv > 0.f ? tp : 0.f;
        float qneg = qv < 0.f ? tp : 0.f;
        float s_sim = qpos * km_s[lane] + qneg * km_s[64 + lane];
        float s_opp = qneg * km_s[lane] + qpos * km_s[64 + lane];
        #pragma unroll
        for (int off = 32; off > 0; off >>= 1) {
            s_sim += __shfl_xor(s_sim, off);
            s_opp += __shfl_xor(s_opp, off);
        }
        float z  = 1.f / (s_sim + 1e-6f);
        float z2 = 1.f / (s_opp + 1e-6f);
        float accum = 0.f;
        #pragma unroll 8
        for (int j = 0; j < 64; ++j) {
            float qp = __shfl(qpos, j);
            float qn = __shfl(qneg, j);
            float a  = sim_side ? qp : qn;
            float bq = sim_side ? qn : qp;
            accum = fmaf(a, kv_s[j * 64 + lane], fmaf(bq, kv_s[(64 + j) * 64 + lane], accum));
        }
        accum *= sim_side ? z : z2;
        ATT[qb + lane] = accum;
    }
}

// ---------------- v 5x5 depthwise conv + gate: PRE = (ATT + conv(V)+bias) * G ----------------
__global__ __launch_bounds__(256) void voutg_kernel(const float* __restrict__ V,
                                                    const float* __restrict__ ATT,
                                                    const float* __restrict__ G,
                                                    const float* __restrict__ dwc_w,
                                                    const float* __restrict__ dwc_b,
                                                    float* __restrict__ PRE) {
    int gid = blockIdx.x * 256 + threadIdx.x;
    int c = gid & (CDIM - 1);
    int m = gid >> 9;
    int dch = c & 63;
    int b = m / NTOK;
    int nsp = m - b * NTOK;
    int y = nsp / HW, x = nsp - y * HW;
    float acc = dwc_b[dch];
    #pragma unroll
    for (int dy = 0; dy < 5; ++dy) {
        int yy = y + dy - 2;
        if (yy < 0 || yy >= HW) continue;
        #pragma unroll
        for (int dx = 0; dx < 5; ++dx) {
            int xx = x + dx - 2;
            if (xx < 0 || xx >= HW) continue;
            acc = fmaf(V[((size_t)(b * NTOK + yy * HW + xx)) * CDIM + c],
                       dwc_w[dch * 25 + dy * 5 + dx], acc);
        }
    }
    PRE[gid] = (ATT[gid] + acc) * G[gid];
}

extern "C" void kernel_launch(void* const* d_in, const int* in_sizes, int n_in,
                              void* d_out, int out_size, void* d_ws, size_t ws_size,
                              hipStream_t stream) {
    const float* x      = (const float*)d_in[0];
    const float* qg_w   = (const float*)d_in[1];
    const float* kv_w   = (const float*)d_in[2];
    const float* proj_w = (const float*)d_in[3];
    const float* proj_b = (const float*)d_in[4];
    const float* dwc_w  = (const float*)d_in[5];
    const float* dwc_b  = (const float*)d_in[6];
    const float* power_p= (const float*)d_in[7];
    const float* scale_p= (const float*)d_in[8];
    const float* enh_w  = (const float*)d_in[9];
    const float* bn_g   = (const float*)d_in[10];
    const float* bn_b   = (const float*)d_in[11];
    const float* ew_p   = (const float*)d_in[12];
    const float* pos    = (const float*)d_in[13];

    const size_t NELEM = (size_t)MTOT * CDIM;   // 12,845,056
    float* ws    = (float*)d_ws;
    float* Qb    = ws;
    float* Gb    = ws + NELEM;
    float* Kb    = ws + 2 * NELEM;
    float* Vb    = ws + 3 * NELEM;
    float* QEb   = ws + 4 * NELEM;      // reused: kvred partials, then ATT
    float* SMALL = ws + 5 * NELEM;
    float* ssum  = SMALL;               // 512
    float* ssq   = SMALL + 512;         // 512
    float* kmean = SMALL + 1024;        // 8192
    float* kvmat = SMALL + 9216;        // 524288
    float* invs  = SMALL + 533504;      // 512
    float* powr  = SMALL + 534016;      // 512
    float* achan = SMALL + 534528;      // 512
    float* bchan = SMALL + 535040;      // 512
    // partials live in the (dead-between-qfin-and-attn) QE region:
    float* PKV   = QEb;                 // 14*64*8192 = 7,340,032 floats
    float* PKM   = QEb + 7340032;       // 14*64*128  = 114,688 floats
    float* ATTb  = QEb;                 // attn output overwrites partials (after reduce)
    float* PREb  = Kb;                  // reuse (K dead after kvred)

    // zero only the atomically-accumulated BN stats
    hipMemsetAsync(SMALL, 0, (size_t)1024 * sizeof(float), stream);

    prep_kernel<<<1, 512, 0, stream>>>(scale_p, power_p, invs, powr);

    dim3 ggrid(196, 8);
    gemm_k512<0><<<ggrid, 256, 0, stream>>>(x, qg_w, Qb, Gb, nullptr, nullptr);
    gemm_k512<1><<<ggrid, 256, 0, stream>>>(x, kv_w, Kb, Vb, pos, invs);

    conv3_kernel<<<50176, 256, 0, stream>>>(Qb, enh_w, QEb);
    stats_kernel<<<392, 256, 0, stream>>>(QEb, ssum, ssq);
    bnprep_kernel<<<1, 512, 0, stream>>>(ssum, ssq, bn_g, bn_b, achan, bchan);
    qfin_kernel<<<50176, 256, 0, stream>>>(Qb, QEb, achan, bchan, invs, ew_p);

    kvred2_kernel<<<dim3(64, 14), 256, 0, stream>>>(Kb, Vb, powr, PKV, PKM);
    kvreduce_kernel<<<2080, 256, 0, stream>>>(PKV, PKM, kvmat, kmean);

    attn_kernel<<<dim3(64, 49), 256, 0, stream>>>(Qb, kvmat, kmean, powr, ATTb);

    voutg_kernel<<<50176, 256, 0, stream>>>(Vb, ATTb, Gb, dwc_w, dwc_b, PREb);

    dim3 pgrid(196, 4);
    gemm_k512<2><<<pgrid, 256, 0, stream>>>(PREb, proj_w, (float*)d_out, nullptr, proj_b, nullptr);
}

// Round 3
// 925.982 us; speedup vs baseline: 2.4070x; 2.0681x over previous
//
#include <hip/hip_runtime.h>
#include <hip/hip_bf16.h>
#include <math.h>

#define CDIM 512
#define NTOK 3136
#define BATCH 8
#define MTOT (BATCH*NTOK)   // 25088
#define NHEAD 8
#define DHEAD 64
#define HW 56

typedef __attribute__((ext_vector_type(8))) short short8;
typedef __attribute__((ext_vector_type(4))) float f32x4;

__device__ __forceinline__ ushort f2bf(float f) {
    union { float f; unsigned int u; } v; v.f = f;
    unsigned int u = v.u + 0x7FFFu + ((v.u >> 16) & 1u);
    return (ushort)(u >> 16);
}

__device__ __forceinline__ void gload_lds16(const ushort* g, ushort* lds) {
    __builtin_amdgcn_global_load_lds((const __attribute__((address_space(1))) void*)g,
                                     (__attribute__((address_space(3))) void*)lds,
                                     16, 0, 0);
}

// ---------------- prep: per-channel inv_scale and power ----------------
__global__ void prep_kernel(const float* __restrict__ scale_p,
                            const float* __restrict__ power_p,
                            float* __restrict__ inv_scale,
                            float* __restrict__ power) {
    int c = threadIdx.x;
    if (c < CDIM) {
        float s = log1pf(expf(scale_p[c]));        // softplus
        inv_scale[c] = 1.0f / s;
        power[c] = 1.0f + 4.0f / (1.0f + expf(-power_p[c]));  // 1+ALPHA*sigmoid
    }
}

// ---------------- fp32 -> bf16 conversion (vectorized) ----------------
__global__ __launch_bounds__(256) void cvt_bf16_kernel(const float* __restrict__ src,
                                                       ushort* __restrict__ dst, int n4) {
    int i = blockIdx.x * 256 + threadIdx.x;
    if (i < n4) {
        float4 f = ((const float4*)src)[i];
        ushort4 o;
        o.x = f2bf(f.x); o.y = f2bf(f.y); o.z = f2bf(f.z); o.w = f2bf(f.w);
        ((ushort4*)dst)[i] = o;
    }
}

// ---------------- bf16 MFMA GEMM: out[m,o] = sum_c A[m,c]*B[o,c] ----------------
// A [M][512] bf16, B [O][512] bf16. 128x128 tile, BK=64, 4 waves (2x2 of 64x64).
// EPI 0: qg  -> out0=Q (o<512), out1=G
// EPI 1: kv  -> out0=K=(acc+pos)*invs (o<512), out1=V; aux0=pos_enc, aux1=invs
// EPI 2: proj-> out0=acc+proj_b; aux0=proj_b
template<int EPI>
__global__ __launch_bounds__(256) void mgemm(const ushort* __restrict__ A,
                                             const ushort* __restrict__ B,
                                             float* __restrict__ out0,
                                             float* __restrict__ out1,
                                             const float* __restrict__ aux0,
                                             const float* __restrict__ aux1) {
    __shared__ ushort At[128 * 64];
    __shared__ ushort Bt[128 * 64];
    const int t = threadIdx.x;
    const int w = t >> 6, l = t & 63;
    const int m0 = blockIdx.x * 128, o0 = blockIdx.y * 128;
    const int wr = w >> 1, wc = w & 1;
    f32x4 acc[4][4] = {};
    const int r8 = l >> 3, sl = l & 7;
    const int ss = sl ^ r8;            // swizzled source slot (involution)

    for (int ks = 0; ks < 8; ++ks) {
        const int k0 = ks * 64;
        #pragma unroll
        for (int c = 0; c < 4; ++c) {
            int rc = (w * 4 + c) * 8 + r8;     // tile row this lane stages
            gload_lds16(A + (size_t)(m0 + rc) * CDIM + k0 + ss * 8, At + (w * 4 + c) * 512);
            gload_lds16(B + (size_t)(o0 + rc) * CDIM + k0 + ss * 8, Bt + (w * 4 + c) * 512);
        }
        __syncthreads();
        #pragma unroll
        for (int kk = 0; kk < 2; ++kk) {
            short8 af[4], bfr[4];
            const int sbase = kk * 4 + (l >> 4);
            #pragma unroll
            for (int i = 0; i < 4; ++i) {
                int row = wr * 64 + i * 16 + (l & 15);
                af[i] = *(const short8*)&At[row * 64 + ((sbase ^ (row & 7)) * 8)];
                int rowb = wc * 64 + i * 16 + (l & 15);
                bfr[i] = *(const short8*)&Bt[rowb * 64 + ((sbase ^ (rowb & 7)) * 8)];
            }
            #pragma unroll
            for (int i = 0; i < 4; ++i)
                #pragma unroll
                for (int j = 0; j < 4; ++j)
                    acc[i][j] = __builtin_amdgcn_mfma_f32_16x16x32_bf16(af[i], bfr[j], acc[i][j], 0, 0, 0);
        }
        __syncthreads();
    }
    #pragma unroll
    for (int i = 0; i < 4; ++i) {
        #pragma unroll
        for (int rr = 0; rr < 4; ++rr) {
            int m = m0 + wr * 64 + i * 16 + (l >> 4) * 4 + rr;
            size_t mrow = (size_t)m * CDIM;
            #pragma unroll
            for (int j = 0; j < 4; ++j) {
                int o = o0 + wc * 64 + j * 16 + (l & 15);
                float v = acc[i][j][rr];
                if (EPI == 0) {
                    if (o < CDIM) out0[mrow + o] = v;
                    else          out1[mrow + o - CDIM] = v;
                } else if (EPI == 1) {
                    if (o < CDIM) {
                        int n = m % NTOK;
                        out0[mrow + o] = (v + aux0[(size_t)n * CDIM + o]) * aux1[o];
                    } else {
                        out1[mrow + o - CDIM] = v;
                    }
                } else {
                    out0[mrow + o] = v + aux0[o];
                }
            }
        }
    }
}

// ---------------- depthwise 3x3 conv on Q (NHWC), zero pad 1 ----------------
__global__ __launch_bounds__(256) void conv3_kernel(const float* __restrict__ Q,
                                                    const float* __restrict__ enh_w,
                                                    float* __restrict__ QE) {
    int gid = blockIdx.x * 256 + threadIdx.x;
    int c = gid & (CDIM - 1);
    int m = gid >> 9;
    int b = m / NTOK;
    int nsp = m - b * NTOK;
    int y = nsp / HW, x = nsp - y * HW;
    float acc = 0.f;
    #pragma unroll
    for (int dy = 0; dy < 3; ++dy) {
        int yy = y + dy - 1;
        if (yy < 0 || yy >= HW) continue;
        #pragma unroll
        for (int dx = 0; dx < 3; ++dx) {
            int xx = x + dx - 1;
            if (xx < 0 || xx >= HW) continue;
            acc = fmaf(Q[((size_t)(b * NTOK + yy * HW + xx)) * CDIM + c],
                       enh_w[c * 9 + dy * 3 + dx], acc);
        }
    }
    QE[gid] = acc;
}

// ---------------- per-channel BN stats (sum, sumsq) ----------------
__global__ __launch_bounds__(256) void stats_kernel(const float* __restrict__ QE,
                                                    float* __restrict__ ssum,
                                                    float* __restrict__ ssq) {
    int c0 = threadIdx.x;
    int rowStart = blockIdx.x * 64;
    float s1a = 0, s2a = 0, s1b = 0, s2b = 0;
    for (int r = 0; r < 64; ++r) {
        size_t base = (size_t)(rowStart + r) * CDIM;
        float va = QE[base + c0];
        float vb = QE[base + c0 + 256];
        s1a += va; s2a += va * va;
        s1b += vb; s2b += vb * vb;
    }
    atomicAdd(&ssum[c0], s1a);       atomicAdd(&ssq[c0], s2a);
    atomicAdd(&ssum[c0 + 256], s1b); atomicAdd(&ssq[c0 + 256], s2b);
}

__global__ void bnprep_kernel(const float* __restrict__ ssum, const float* __restrict__ ssq,
                              const float* __restrict__ bn_g, const float* __restrict__ bn_b,
                              float* __restrict__ achan, float* __restrict__ bchan) {
    int c = threadIdx.x;
    if (c < CDIM) {
        const float invM = 1.0f / (float)MTOT;
        float mean = ssum[c] * invM;
        float var  = ssq[c] * invM - mean * mean;
        float a = bn_g[c] * rsqrtf(var + 1e-5f);
        achan[c] = a;
        bchan[c] = bn_b[c] - mean * a;
    }
}

// ---------------- finalize q: Q = (Q + ew*relu(a*QE+b)) * inv_scale ----------------
__global__ __launch_bounds__(256) void qfin_kernel(float* __restrict__ Q,
                                                   const float* __restrict__ QE,
                                                   const float* __restrict__ achan,
                                                   const float* __restrict__ bchan,
                                                   const float* __restrict__ inv_scale,
                                                   const float* __restrict__ ewp) {
    int gid = blockIdx.x * 256 + threadIdx.x;
    int c = gid & (CDIM - 1);
    float ew = ewp[0];
    float e = fmaxf(fmaf(achan[c], QE[gid], bchan[c]), 0.f);
    Q[gid] = fmaf(ew, e, Q[gid]) * inv_scale[c];
}

// ---------------- kvred v2: tiled LDS, KF once, TRANSPOSED partials ----------------
// PKV[(chunk*64+bh)][e=64][d=128] raw sums; PKM[(chunk*64+bh)][128] kf col sums.
__global__ __launch_bounds__(256) void kvred2_kernel(const float* __restrict__ K,
                                                     const float* __restrict__ V,
                                                     const float* __restrict__ power,
                                                     float* __restrict__ PKV,
                                                     float* __restrict__ PKM) {
    int bh = blockIdx.x;
    int b = bh >> 3, head = bh & 7;
    int chunk = blockIdx.y;       // 0..13
    int t = threadIdx.x;
    __shared__ float Ks[32][64];
    __shared__ float Vs[32][64];
    __shared__ float KFs[32][128];

    const int dkf = t & 127;
    const float p_kf = power[head * 64 + (dkf & 63)];
    const bool neg_kf = dkf >= 64;
    const int rbase = t >> 7;

    const int d0 = (t >> 3) * 4;
    const int e0 = (t & 7) * 8;
    float acc[4][8];
    #pragma unroll
    for (int i = 0; i < 4; ++i)
        #pragma unroll
        for (int j = 0; j < 8; ++j) acc[i][j] = 0.f;
    float kmsum = 0.f;

    const int nbase = b * NTOK + chunk * 224;
    for (int tile = 0; tile < 7; ++tile) {
        int n0 = nbase + tile * 32;
        #pragma unroll
        for (int i = 0; i < 2; ++i) {
            int f = t + i * 256;
            int row = f >> 4, c4 = (f & 15) * 4;
            size_t g = (size_t)(n0 + row) * CDIM + head * 64 + c4;
            *(float4*)&Ks[row][c4] = *(const float4*)(K + g);
            *(float4*)&Vs[row][c4] = *(const float4*)(V + g);
        }
        __syncthreads();
        #pragma unroll
        for (int kk = 0; kk < 16; ++kk) {
            int row = 2 * kk + rbase;
            float kraw = Ks[row][dkf & 63];
            float kx = neg_kf ? -kraw : kraw;
            KFs[row][dkf] = kx > 0.f ? __powf(kx, p_kf) : 0.f;
        }
        __syncthreads();
        if (t < 128) {
            #pragma unroll
            for (int r = 0; r < 32; ++r) kmsum += KFs[r][t];
        }
        #pragma unroll
        for (int r = 0; r < 32; ++r) {
            float4 kf4 = *(const float4*)&KFs[r][d0];
            float4 va  = *(const float4*)&Vs[r][e0];
            float4 vb  = *(const float4*)&Vs[r][e0 + 4];
            float kk4[4] = {kf4.x, kf4.y, kf4.z, kf4.w};
            float vv[8]  = {va.x, va.y, va.z, va.w, vb.x, vb.y, vb.z, vb.w};
            #pragma unroll
            for (int i = 0; i < 4; ++i)
                #pragma unroll
                for (int j = 0; j < 8; ++j)
                    acc[i][j] = fmaf(kk4[i], vv[j], acc[i][j]);
        }
        __syncthreads();
    }
    size_t base = ((size_t)(chunk * 64 + bh)) * 8192;
    #pragma unroll
    for (int j = 0; j < 8; ++j) {
        *(float4*)(PKV + base + (size_t)(e0 + j) * 128 + d0) =
            make_float4(acc[0][j], acc[1][j], acc[2][j], acc[3][j]);
    }
    if (t < 128) PKM[(chunk * 64 + bh) * 128 + t] = kmsum;
}

// reduce partials: kvT[bh][e=64][d=128], kmean[bh][128]
__global__ __launch_bounds__(256) void kvreduce_kernel(const float* __restrict__ PKV,
                                                       const float* __restrict__ PKM,
                                                       float* __restrict__ kvT,
                                                       float* __restrict__ kmean) {
    int gid = blockIdx.x * 256 + threadIdx.x;
    const float inv_n = 1.0f / (float)NTOK;
    if (gid < 524288) {
        float s = 0.f;
        #pragma unroll
        for (int c = 0; c < 14; ++c) s += PKV[(size_t)c * 524288 + gid];
        kvT[gid] = s * inv_n;
    } else if (gid < 532480) {
        int j = gid - 524288;
        float s = 0.f;
        #pragma unroll
        for (int c = 0; c < 14; ++c) s += PKM[c * 8192 + j];
        kmean[j] = s * inv_n;
    }
}

// ---------------- attention apply via MFMA: [64 tok][128] x [128][80] ----------------
// BT rows: 0..31 kv1 cols; 32..63 kv2 cols (d^64); 64 kmean; 65 kmean^64; 66..79 zero.
__global__ __launch_bounds__(256) void attn_mfma_kernel(const float* __restrict__ Q,
                                                        const float* __restrict__ kvT,
                                                        const float* __restrict__ kmean,
                                                        const float* __restrict__ power,
                                                        float* __restrict__ ATT) {
    __shared__ ushort QF[64 * 128];   // [tok][128] bf16, 16B-slot XOR swizzle by (tok&7)
    __shared__ ushort BT[80 * 128];   // [col][128] bf16, same swizzle by (col&7)
    const int bh = blockIdx.x, tb = blockIdx.y;
    const int b = bh >> 3, head = bh & 7;
    const int t = threadIdx.x;
    const int w = t >> 6, l = t & 63;

    // --- build QF (each wave owns tok = 4i+w, lane owns channel c) ---
    const int c = l;
    const float p = power[head * 64 + c];
    #pragma unroll
    for (int i = 0; i < 16; ++i) {
        int tok = i * 4 + w;
        float q = Q[((size_t)(b * NTOK + tb * 64 + tok)) * CDIM + head * 64 + c];
        float ax = fabsf(q);
        float tp = ax > 0.f ? __powf(ax, p) : 0.f;
        float qp = q > 0.f ? tp : 0.f;
        float qn = q < 0.f ? tp : 0.f;
        int sw = tok & 7;
        QF[tok * 128 + (((c >> 3) ^ sw) * 8) + (c & 7)]       = f2bf(qp);
        QF[tok * 128 + ((((c >> 3) + 8) ^ sw) * 8) + (c & 7)] = f2bf(qn);
    }
    // --- build BT ---
    #pragma unroll
    for (int i = 0; i < 5; ++i) {
        int qc = i * 256 + t;            // 0..1279 chunk id
        int row = qc >> 4, s = qc & 15;
        int ls = s ^ (row & 7);          // logical 8-elem slot
        int d0 = ls * 8;
        short8 ov;
        if (row < 64) {
            int dsel = (row >= 32) ? (d0 ^ 64) : d0;
            const float* src = kvT + (size_t)bh * 8192 + row * 128 + dsel;
            #pragma unroll
            for (int e = 0; e < 8; ++e) ov[e] = (short)f2bf(src[e]);
        } else if (row == 64) {
            const float* src = kmean + bh * 128 + d0;
            #pragma unroll
            for (int e = 0; e < 8; ++e) ov[e] = (short)f2bf(src[e]);
        } else if (row == 65) {
            const float* src = kmean + bh * 128 + (d0 ^ 64);
            #pragma unroll
            for (int e = 0; e < 8; ++e) ov[e] = (short)f2bf(src[e]);
        } else {
            #pragma unroll
            for (int e = 0; e < 8; ++e) ov[e] = 0;
        }
        *(short8*)&BT[row * 128 + s * 8] = ov;
    }
    __syncthreads();

    // --- MFMA: wave w computes toks [w*16, w*16+16) x 80 cols ---
    f32x4 acc[5] = {};
    #pragma unroll
    for (int kk = 0; kk < 4; ++kk) {
        int sbase = kk * 4 + (l >> 4);
        int rowa = w * 16 + (l & 15);
        short8 af = *(const short8*)&QF[rowa * 128 + ((sbase ^ (rowa & 7)) * 8)];
        #pragma unroll
        for (int j = 0; j < 5; ++j) {
            int rowb = j * 16 + (l & 15);
            short8 bf = *(const short8*)&BT[rowb * 128 + ((sbase ^ (rowb & 7)) * 8)];
            acc[j] = __builtin_amdgcn_mfma_f32_16x16x32_bf16(af, bf, acc[j], 0, 0, 0);
        }
    }
    // --- epilogue: z from n-frag 4 cols 64/65, scale and store ---
    #pragma unroll
    for (int rr = 0; rr < 4; ++rr) {
        float ssim = __shfl(acc[4][rr], (l & 48));
        float sopp = __shfl(acc[4][rr], (l & 48) + 1);
        float zs = 1.f / (ssim + 1e-6f);
        float zo = 1.f / (sopp + 1e-6f);
        int tok = tb * 64 + w * 16 + (l >> 4) * 4 + rr;
        size_t base = ((size_t)(b * NTOK + tok)) * CDIM + head * 64;
        #pragma unroll
        for (int j = 0; j < 4; ++j) {
            int e = j * 16 + (l & 15);
            ATT[base + e] = acc[j][rr] * (j < 2 ? zs : zo);
        }
    }
}

// ---------------- v 5x5 depthwise conv + gate: PREbf = bf16((ATT + conv(V)+b) * G) ----------------
__global__ __launch_bounds__(256) void voutg_kernel(const float* __restrict__ V,
                                                    const float* __restrict__ ATT,
                                                    const float* __restrict__ G,
                                                    const float* __restrict__ dwc_w,
                                                    const float* __restrict__ dwc_b,
                                                    ushort* __restrict__ PRE) {
    int gid = blockIdx.x * 256 + threadIdx.x;
    int c = gid & (CDIM - 1);
    int m = gid >> 9;
    int dch = c & 63;
    int b = m / NTOK;
    int nsp = m - b * NTOK;
    int y = nsp / HW, x = nsp - y * HW;
    float acc = dwc_b[dch];
    #pragma unroll
    for (int dy = 0; dy < 5; ++dy) {
        int yy = y + dy - 2;
        if (yy < 0 || yy >= HW) continue;
        #pragma unroll
        for (int dx = 0; dx < 5; ++dx) {
            int xx = x + dx - 2;
            if (xx < 0 || xx >= HW) continue;
            acc = fmaf(V[((size_t)(b * NTOK + yy * HW + xx)) * CDIM + c],
                       dwc_w[dch * 25 + dy * 5 + dx], acc);
        }
    }
    PRE[gid] = f2bf((ATT[gid] + acc) * G[gid]);
}

extern "C" void kernel_launch(void* const* d_in, const int* in_sizes, int n_in,
                              void* d_out, int out_size, void* d_ws, size_t ws_size,
                              hipStream_t stream) {
    const float* x      = (const float*)d_in[0];
    const float* qg_w   = (const float*)d_in[1];
    const float* kv_w   = (const float*)d_in[2];
    const float* proj_w = (const float*)d_in[3];
    const float* proj_b = (const float*)d_in[4];
    const float* dwc_w  = (const float*)d_in[5];
    const float* dwc_b  = (const float*)d_in[6];
    const float* power_p= (const float*)d_in[7];
    const float* scale_p= (const float*)d_in[8];
    const float* enh_w  = (const float*)d_in[9];
    const float* bn_g   = (const float*)d_in[10];
    const float* bn_b   = (const float*)d_in[11];
    const float* ew_p   = (const float*)d_in[12];
    const float* pos    = (const float*)d_in[13];

    const size_t NELEM = (size_t)MTOT * CDIM;   // 12,845,056
    float* ws    = (float*)d_ws;
    float* Qb    = ws;
    float* Gb    = ws + NELEM;
    float* Kb    = ws + 2 * NELEM;
    float* Vb    = ws + 3 * NELEM;
    float* QEb   = ws + 4 * NELEM;      // reused: Xbf, QE, PKV/PKM, ATT
    float* SMALL = ws + 5 * NELEM;
    float* ssum  = SMALL;               // 512
    float* ssq   = SMALL + 512;         // 512
    float* kmean = SMALL + 1024;        // 8192
    float* kvT   = SMALL + 9216;        // 524288 ([bh][e][d])
    float* invs  = SMALL + 533504;      // 512
    float* powr  = SMALL + 534016;      // 512
    float* achan = SMALL + 534528;      // 512
    float* bchan = SMALL + 535040;      // 512
    ushort* Wqg  = (ushort*)(SMALL + 535552);    // 524288 bf16
    ushort* Wkv  = (ushort*)(SMALL + 797696);    // 524288 bf16
    ushort* Wproj= (ushort*)(SMALL + 1059840);   // 262144 bf16

    ushort* Xbf  = (ushort*)QEb;        // x in bf16 (dead after kv gemm; conv3 overwrites)
    float* PKV   = QEb;                 // 7,340,032 floats (after QE dead)
    float* PKM   = QEb + 7340032;       // 114,688 floats
    float* ATTb  = QEb;                 // attn output (partials dead after kvreduce)
    ushort* PREbf= (ushort*)Kb;         // proj input bf16 (K dead after kvred2)

    hipMemsetAsync(SMALL, 0, (size_t)1024 * sizeof(float), stream);

    prep_kernel<<<1, 512, 0, stream>>>(scale_p, power_p, invs, powr);

    cvt_bf16_kernel<<<12544, 256, 0, stream>>>(x, Xbf, 3211264);
    cvt_bf16_kernel<<<512, 256, 0, stream>>>(qg_w, Wqg, 131072);
    cvt_bf16_kernel<<<512, 256, 0, stream>>>(kv_w, Wkv, 131072);
    cvt_bf16_kernel<<<256, 256, 0, stream>>>(proj_w, Wproj, 65536);

    dim3 ggrid(196, 8);
    mgemm<0><<<ggrid, 256, 0, stream>>>(Xbf, Wqg, Qb, Gb, nullptr, nullptr);
    mgemm<1><<<ggrid, 256, 0, stream>>>(Xbf, Wkv, Kb, Vb, pos, invs);

    conv3_kernel<<<50176, 256, 0, stream>>>(Qb, enh_w, QEb);
    stats_kernel<<<392, 256, 0, stream>>>(QEb, ssum, ssq);
    bnprep_kernel<<<1, 512, 0, stream>>>(ssum, ssq, bn_g, bn_b, achan, bchan);
    qfin_kernel<<<50176, 256, 0, stream>>>(Qb, QEb, achan, bchan, invs, ew_p);

    kvred2_kernel<<<dim3(64, 14), 256, 0, stream>>>(Kb, Vb, powr, PKV, PKM);
    kvreduce_kernel<<<2080, 256, 0, stream>>>(PKV, PKM, kvT, kmean);

    attn_mfma_kernel<<<dim3(64, 49), 256, 0, stream>>>(Qb, kvT, kmean, powr, ATTb);

    voutg_kernel<<<50176, 256, 0, stream>>>(Vb, ATTb, Gb, dwc_w, dwc_b, PREbf);

    dim3 pgrid(196, 4);
    mgemm<2><<<pgrid, 256, 0, stream>>>(PREbf, Wproj, (float*)d_out, nullptr, proj_b, nullptr);
}

// Round 4
// 640.973 us; speedup vs baseline: 3.4773x; 1.4447x over previous
//
#include <hip/hip_runtime.h>
#include <hip/hip_bf16.h>
#include <math.h>

#define CDIM 512
#define NTOK 3136
#define BATCH 8
#define MTOT (BATCH*NTOK)   // 25088
#define NHEAD 8
#define DHEAD 64
#define HW 56

typedef __attribute__((ext_vector_type(8))) short short8;
typedef __attribute__((ext_vector_type(4))) float f32x4;

__device__ __forceinline__ ushort f2bf(float f) {
    union { float f; unsigned int u; } v; v.f = f;
    unsigned int u = v.u + 0x7FFFu + ((v.u >> 16) & 1u);
    return (ushort)(u >> 16);
}

__device__ __forceinline__ void gload_lds16(const ushort* g, ushort* lds) {
    __builtin_amdgcn_global_load_lds((const __attribute__((address_space(1))) void*)g,
                                     (__attribute__((address_space(3))) void*)lds,
                                     16, 0, 0);
}

// ---------------- prep: per-channel inv_scale and power ----------------
__global__ void prep_kernel(const float* __restrict__ scale_p,
                            const float* __restrict__ power_p,
                            float* __restrict__ inv_scale,
                            float* __restrict__ power) {
    int c = threadIdx.x;
    if (c < CDIM) {
        float s = log1pf(expf(scale_p[c]));        // softplus
        inv_scale[c] = 1.0f / s;
        power[c] = 1.0f + 4.0f / (1.0f + expf(-power_p[c]));  // 1+ALPHA*sigmoid
    }
}

// ---------------- fp32 -> bf16 conversion (vectorized) ----------------
__global__ __launch_bounds__(256) void cvt_bf16_kernel(const float* __restrict__ src,
                                                       ushort* __restrict__ dst, int n4) {
    int i = blockIdx.x * 256 + threadIdx.x;
    if (i < n4) {
        float4 f = ((const float4*)src)[i];
        ushort4 o;
        o.x = f2bf(f.x); o.y = f2bf(f.y); o.z = f2bf(f.z); o.w = f2bf(f.w);
        ((ushort4*)dst)[i] = o;
    }
}

// ---------------- bf16 MFMA GEMM: out[m,o] = sum_c A[m,c]*B[o,c] ----------------
template<int EPI>
__global__ __launch_bounds__(256) void mgemm(const ushort* __restrict__ A,
                                             const ushort* __restrict__ B,
                                             float* __restrict__ out0,
                                             float* __restrict__ out1,
                                             const float* __restrict__ aux0,
                                             const float* __restrict__ aux1) {
    __shared__ ushort At[128 * 64];
    __shared__ ushort Bt[128 * 64];
    const int t = threadIdx.x;
    const int w = t >> 6, l = t & 63;
    const int m0 = blockIdx.x * 128, o0 = blockIdx.y * 128;
    const int wr = w >> 1, wc = w & 1;
    f32x4 acc[4][4] = {};
    const int r8 = l >> 3, sl = l & 7;
    const int ss = sl ^ r8;            // swizzled source slot (involution)

    for (int ks = 0; ks < 8; ++ks) {
        const int k0 = ks * 64;
        #pragma unroll
        for (int c = 0; c < 4; ++c) {
            int rc = (w * 4 + c) * 8 + r8;     // tile row this lane stages
            gload_lds16(A + (size_t)(m0 + rc) * CDIM + k0 + ss * 8, At + (w * 4 + c) * 512);
            gload_lds16(B + (size_t)(o0 + rc) * CDIM + k0 + ss * 8, Bt + (w * 4 + c) * 512);
        }
        __syncthreads();
        #pragma unroll
        for (int kk = 0; kk < 2; ++kk) {
            short8 af[4], bfr[4];
            const int sbase = kk * 4 + (l >> 4);
            #pragma unroll
            for (int i = 0; i < 4; ++i) {
                int row = wr * 64 + i * 16 + (l & 15);
                af[i] = *(const short8*)&At[row * 64 + ((sbase ^ (row & 7)) * 8)];
                int rowb = wc * 64 + i * 16 + (l & 15);
                bfr[i] = *(const short8*)&Bt[rowb * 64 + ((sbase ^ (rowb & 7)) * 8)];
            }
            #pragma unroll
            for (int i = 0; i < 4; ++i)
                #pragma unroll
                for (int j = 0; j < 4; ++j)
                    acc[i][j] = __builtin_amdgcn_mfma_f32_16x16x32_bf16(af[i], bfr[j], acc[i][j], 0, 0, 0);
        }
        __syncthreads();
    }
    #pragma unroll
    for (int i = 0; i < 4; ++i) {
        #pragma unroll
        for (int rr = 0; rr < 4; ++rr) {
            int m = m0 + wr * 64 + i * 16 + (l >> 4) * 4 + rr;
            size_t mrow = (size_t)m * CDIM;
            #pragma unroll
            for (int j = 0; j < 4; ++j) {
                int o = o0 + wc * 64 + j * 16 + (l & 15);
                float v = acc[i][j][rr];
                if (EPI == 0) {
                    if (o < CDIM) out0[mrow + o] = v;
                    else          out1[mrow + o - CDIM] = v;
                } else if (EPI == 1) {
                    if (o < CDIM) {
                        int n = m % NTOK;
                        out0[mrow + o] = (v + aux0[(size_t)n * CDIM + o]) * aux1[o];
                    } else {
                        out1[mrow + o - CDIM] = v;
                    }
                } else {
                    out0[mrow + o] = v + aux0[o];
                }
            }
        }
    }
}

// ---------------- fused 3x3 depthwise conv + BN-stats accumulation ----------------
// Block: 256 threads = one x-position, 512 channels (2/thread). Grid (56, 32): x, (b*4+ychunk).
__global__ __launch_bounds__(256) void conv3s_kernel(const float* __restrict__ Q,
                                                     const float* __restrict__ enh_w,
                                                     float* __restrict__ QE,
                                                     float* __restrict__ ssum,
                                                     float* __restrict__ ssq) {
    const int t = threadIdx.x;
    const int c0 = t * 2;
    const int xpos = blockIdx.x;
    const int byc = blockIdx.y;
    const int b = byc >> 2, yc = byc & 3;
    const int y0 = yc * 14;

    float wgt[9][2];
    #pragma unroll
    for (int tap = 0; tap < 9; ++tap) {
        wgt[tap][0] = enh_w[c0 * 9 + tap];
        wgt[tap][1] = enh_w[(c0 + 1) * 9 + tap];
    }
    const size_t base = (size_t)b * NTOK * CDIM + c0;

    float2 win[3][3];
    auto ldrow = [&](int yy, float2* dst) {
        #pragma unroll
        for (int dx = 0; dx < 3; ++dx) {
            int xx = xpos + dx - 1;
            bool ok = (yy >= 0 && yy < HW && xx >= 0 && xx < HW);
            dst[dx] = ok ? *(const float2*)(Q + base + ((size_t)(yy * HW + xx) << 9))
                         : make_float2(0.f, 0.f);
        }
    };
    ldrow(y0 - 1, win[0]);
    ldrow(y0,     win[1]);

    float s1a = 0.f, s2a = 0.f, s1b = 0.f, s2b = 0.f;
    #pragma unroll
    for (int i = 0; i < 14; ++i) {
        int y = y0 + i;
        ldrow(y + 1, win[(i + 2) % 3]);
        float a0 = 0.f, a1 = 0.f;
        #pragma unroll
        for (int dy = 0; dy < 3; ++dy) {
            float2* row = win[(i + dy) % 3];   // row y+dy-1
            #pragma unroll
            for (int dx = 0; dx < 3; ++dx) {
                a0 = fmaf(row[dx].x, wgt[dy * 3 + dx][0], a0);
                a1 = fmaf(row[dx].y, wgt[dy * 3 + dx][1], a1);
            }
        }
        *(float2*)(QE + base + ((size_t)(y * HW + xpos) << 9)) = make_float2(a0, a1);
        s1a += a0; s2a += a0 * a0;
        s1b += a1; s2b += a1 * a1;
    }
    atomicAdd(&ssum[c0], s1a);     atomicAdd(&ssq[c0], s2a);
    atomicAdd(&ssum[c0 + 1], s1b); atomicAdd(&ssq[c0 + 1], s2b);
}

__global__ void bnprep_kernel(const float* __restrict__ ssum, const float* __restrict__ ssq,
                              const float* __restrict__ bn_g, const float* __restrict__ bn_b,
                              float* __restrict__ achan, float* __restrict__ bchan) {
    int c = threadIdx.x;
    if (c < CDIM) {
        const float invM = 1.0f / (float)MTOT;
        float mean = ssum[c] * invM;
        float var  = ssq[c] * invM - mean * mean;
        float a = bn_g[c] * rsqrtf(var + 1e-5f);
        achan[c] = a;
        bchan[c] = bn_b[c] - mean * a;
    }
}

// ---------------- finalize q: Q = (Q + ew*relu(a*QE+b)) * inv_scale ----------------
__global__ __launch_bounds__(256) void qfin_kernel(float* __restrict__ Q,
                                                   const float* __restrict__ QE,
                                                   const float* __restrict__ achan,
                                                   const float* __restrict__ bchan,
                                                   const float* __restrict__ inv_scale,
                                                   const float* __restrict__ ewp) {
    int gid = blockIdx.x * 256 + threadIdx.x;
    int c = gid & (CDIM - 1);
    float ew = ewp[0];
    float e = fmaxf(fmaf(achan[c], QE[gid], bchan[c]), 0.f);
    Q[gid] = fmaf(ew, e, Q[gid]) * inv_scale[c];
}

// ---------------- kvred v2: tiled LDS, KF once, TRANSPOSED partials ----------------
__global__ __launch_bounds__(256) void kvred2_kernel(const float* __restrict__ K,
                                                     const float* __restrict__ V,
                                                     const float* __restrict__ power,
                                                     float* __restrict__ PKV,
                                                     float* __restrict__ PKM) {
    int bh = blockIdx.x;
    int b = bh >> 3, head = bh & 7;
    int chunk = blockIdx.y;       // 0..13
    int t = threadIdx.x;
    __shared__ float Ks[32][64];
    __shared__ float Vs[32][64];
    __shared__ float KFs[32][128];

    const int dkf = t & 127;
    const float p_kf = power[head * 64 + (dkf & 63)];
    const bool neg_kf = dkf >= 64;
    const int rbase = t >> 7;

    const int d0 = (t >> 3) * 4;
    const int e0 = (t & 7) * 8;
    float acc[4][8];
    #pragma unroll
    for (int i = 0; i < 4; ++i)
        #pragma unroll
        for (int j = 0; j < 8; ++j) acc[i][j] = 0.f;
    float kmsum = 0.f;

    const int nbase = b * NTOK + chunk * 224;
    for (int tile = 0; tile < 7; ++tile) {
        int n0 = nbase + tile * 32;
        #pragma unroll
        for (int i = 0; i < 2; ++i) {
            int f = t + i * 256;
            int row = f >> 4, c4 = (f & 15) * 4;
            size_t g = (size_t)(n0 + row) * CDIM + head * 64 + c4;
            *(float4*)&Ks[row][c4] = *(const float4*)(K + g);
            *(float4*)&Vs[row][c4] = *(const float4*)(V + g);
        }
        __syncthreads();
        #pragma unroll
        for (int kk = 0; kk < 16; ++kk) {
            int row = 2 * kk + rbase;
            float kraw = Ks[row][dkf & 63];
            float kx = neg_kf ? -kraw : kraw;
            KFs[row][dkf] = kx > 0.f ? __powf(kx, p_kf) : 0.f;
        }
        __syncthreads();
        if (t < 128) {
            #pragma unroll
            for (int r = 0; r < 32; ++r) kmsum += KFs[r][t];
        }
        #pragma unroll
        for (int r = 0; r < 32; ++r) {
            float4 kf4 = *(const float4*)&KFs[r][d0];
            float4 va  = *(const float4*)&Vs[r][e0];
            float4 vb  = *(const float4*)&Vs[r][e0 + 4];
            float kk4[4] = {kf4.x, kf4.y, kf4.z, kf4.w};
            float vv[8]  = {va.x, va.y, va.z, va.w, vb.x, vb.y, vb.z, vb.w};
            #pragma unroll
            for (int i = 0; i < 4; ++i)
                #pragma unroll
                for (int j = 0; j < 8; ++j)
                    acc[i][j] = fmaf(kk4[i], vv[j], acc[i][j]);
        }
        __syncthreads();
    }
    size_t base = ((size_t)(chunk * 64 + bh)) * 8192;
    #pragma unroll
    for (int j = 0; j < 8; ++j) {
        *(float4*)(PKV + base + (size_t)(e0 + j) * 128 + d0) =
            make_float4(acc[0][j], acc[1][j], acc[2][j], acc[3][j]);
    }
    if (t < 128) PKM[(chunk * 64 + bh) * 128 + t] = kmsum;
}

// reduce partials: kvT[bh][e=64][d=128], kmean[bh][128]
__global__ __launch_bounds__(256) void kvreduce_kernel(const float* __restrict__ PKV,
                                                       const float* __restrict__ PKM,
                                                       float* __restrict__ kvT,
                                                       float* __restrict__ kmean) {
    int gid = blockIdx.x * 256 + threadIdx.x;
    const float inv_n = 1.0f / (float)NTOK;
    if (gid < 524288) {
        float s = 0.f;
        #pragma unroll
        for (int c = 0; c < 14; ++c) s += PKV[(size_t)c * 524288 + gid];
        kvT[gid] = s * inv_n;
    } else if (gid < 532480) {
        int j = gid - 524288;
        float s = 0.f;
        #pragma unroll
        for (int c = 0; c < 14; ++c) s += PKM[c * 8192 + j];
        kmean[j] = s * inv_n;
    }
}

// ---------------- attention apply via MFMA: [64 tok][128] x [128][80] ----------------
__global__ __launch_bounds__(256) void attn_mfma_kernel(const float* __restrict__ Q,
                                                        const float* __restrict__ kvT,
                                                        const float* __restrict__ kmean,
                                                        const float* __restrict__ power,
                                                        float* __restrict__ ATT) {
    __shared__ ushort QF[64 * 128];
    __shared__ ushort BT[80 * 128];
    const int bh = blockIdx.x, tb = blockIdx.y;
    const int b = bh >> 3, head = bh & 7;
    const int t = threadIdx.x;
    const int w = t >> 6, l = t & 63;

    const int c = l;
    const float p = power[head * 64 + c];
    #pragma unroll
    for (int i = 0; i < 16; ++i) {
        int tok = i * 4 + w;
        float q = Q[((size_t)(b * NTOK + tb * 64 + tok)) * CDIM + head * 64 + c];
        float ax = fabsf(q);
        float tp = ax > 0.f ? __powf(ax, p) : 0.f;
        float qp = q > 0.f ? tp : 0.f;
        float qn = q < 0.f ? tp : 0.f;
        int sw = tok & 7;
        QF[tok * 128 + (((c >> 3) ^ sw) * 8) + (c & 7)]       = f2bf(qp);
        QF[tok * 128 + ((((c >> 3) + 8) ^ sw) * 8) + (c & 7)] = f2bf(qn);
    }
    #pragma unroll
    for (int i = 0; i < 5; ++i) {
        int qc = i * 256 + t;
        int row = qc >> 4, s = qc & 15;
        int ls = s ^ (row & 7);
        int d0 = ls * 8;
        short8 ov;
        if (row < 64) {
            int dsel = (row >= 32) ? (d0 ^ 64) : d0;
            const float* src = kvT + (size_t)bh * 8192 + row * 128 + dsel;
            #pragma unroll
            for (int e = 0; e < 8; ++e) ov[e] = (short)f2bf(src[e]);
        } else if (row == 64) {
            const float* src = kmean + bh * 128 + d0;
            #pragma unroll
            for (int e = 0; e < 8; ++e) ov[e] = (short)f2bf(src[e]);
        } else if (row == 65) {
            const float* src = kmean + bh * 128 + (d0 ^ 64);
            #pragma unroll
            for (int e = 0; e < 8; ++e) ov[e] = (short)f2bf(src[e]);
        } else {
            #pragma unroll
            for (int e = 0; e < 8; ++e) ov[e] = 0;
        }
        *(short8*)&BT[row * 128 + s * 8] = ov;
    }
    __syncthreads();

    f32x4 acc[5] = {};
    #pragma unroll
    for (int kk = 0; kk < 4; ++kk) {
        int sbase = kk * 4 + (l >> 4);
        int rowa = w * 16 + (l & 15);
        short8 af = *(const short8*)&QF[rowa * 128 + ((sbase ^ (rowa & 7)) * 8)];
        #pragma unroll
        for (int j = 0; j < 5; ++j) {
            int rowb = j * 16 + (l & 15);
            short8 bf = *(const short8*)&BT[rowb * 128 + ((sbase ^ (rowb & 7)) * 8)];
            acc[j] = __builtin_amdgcn_mfma_f32_16x16x32_bf16(af, bf, acc[j], 0, 0, 0);
        }
    }
    #pragma unroll
    for (int rr = 0; rr < 4; ++rr) {
        float ssim = __shfl(acc[4][rr], (l & 48));
        float sopp = __shfl(acc[4][rr], (l & 48) + 1);
        float zs = 1.f / (ssim + 1e-6f);
        float zo = 1.f / (sopp + 1e-6f);
        int tok = tb * 64 + w * 16 + (l >> 4) * 4 + rr;
        size_t base = ((size_t)(b * NTOK + tok)) * CDIM + head * 64;
        #pragma unroll
        for (int j = 0; j < 4; ++j) {
            int e = j * 16 + (l & 15);
            ATT[base + e] = acc[j][rr] * (j < 2 ? zs : zo);
        }
    }
}

// ---------------- v2 5x5 depthwise conv + gate, register-rolling window ----------------
// Block: 256 threads = one x-position, 512 channels (2/thread). Grid (56, 32): x, (b*4+ychunk).
__global__ __launch_bounds__(256) void voutg2_kernel(const float* __restrict__ V,
                                                     const float* __restrict__ ATT,
                                                     const float* __restrict__ G,
                                                     const float* __restrict__ dwc_w,
                                                     const float* __restrict__ dwc_b,
                                                     ushort* __restrict__ PRE) {
    const int t = threadIdx.x;
    const int c0 = t * 2;
    const int xpos = blockIdx.x;
    const int byc = blockIdx.y;
    const int b = byc >> 2, yc = byc & 3;
    const int y0 = yc * 14;
    const int dch = c0 & 63;

    float wgt[25][2];
    #pragma unroll
    for (int tap = 0; tap < 25; ++tap) {
        wgt[tap][0] = dwc_w[dch * 25 + tap];
        wgt[tap][1] = dwc_w[(dch + 1) * 25 + tap];
    }
    const float bias0 = dwc_b[dch], bias1 = dwc_b[dch + 1];
    const size_t base = (size_t)b * NTOK * CDIM + c0;

    float2 win[5][5];
    auto ldrow = [&](int yy, float2* dst) {
        #pragma unroll
        for (int dx = 0; dx < 5; ++dx) {
            int xx = xpos + dx - 2;
            bool ok = (yy >= 0 && yy < HW && xx >= 0 && xx < HW);
            dst[dx] = ok ? *(const float2*)(V + base + ((size_t)(yy * HW + xx) << 9))
                         : make_float2(0.f, 0.f);
        }
    };
    ldrow(y0 - 2, win[0]);
    ldrow(y0 - 1, win[1]);
    ldrow(y0,     win[2]);
    ldrow(y0 + 1, win[3]);

    #pragma unroll
    for (int i = 0; i < 14; ++i) {
        int y = y0 + i;
        ldrow(y + 2, win[(i + 4) % 5]);
        float a0 = bias0, a1 = bias1;
        #pragma unroll
        for (int dy = 0; dy < 5; ++dy) {
            float2* row = win[(i + dy) % 5];   // row y+dy-2
            #pragma unroll
            for (int dx = 0; dx < 5; ++dx) {
                a0 = fmaf(row[dx].x, wgt[dy * 5 + dx][0], a0);
                a1 = fmaf(row[dx].y, wgt[dy * 5 + dx][1], a1);
            }
        }
        size_t oidx = base + ((size_t)(y * HW + xpos) << 9);
        float2 att = *(const float2*)(ATT + oidx);
        float2 g   = *(const float2*)(G + oidx);
        ushort2 o;
        o.x = f2bf((att.x + a0) * g.x);
        o.y = f2bf((att.y + a1) * g.y);
        *(ushort2*)(PRE + oidx) = o;
    }
}

extern "C" void kernel_launch(void* const* d_in, const int* in_sizes, int n_in,
                              void* d_out, int out_size, void* d_ws, size_t ws_size,
                              hipStream_t stream) {
    const float* x      = (const float*)d_in[0];
    const float* qg_w   = (const float*)d_in[1];
    const float* kv_w   = (const float*)d_in[2];
    const float* proj_w = (const float*)d_in[3];
    const float* proj_b = (const float*)d_in[4];
    const float* dwc_w  = (const float*)d_in[5];
    const float* dwc_b  = (const float*)d_in[6];
    const float* power_p= (const float*)d_in[7];
    const float* scale_p= (const float*)d_in[8];
    const float* enh_w  = (const float*)d_in[9];
    const float* bn_g   = (const float*)d_in[10];
    const float* bn_b   = (const float*)d_in[11];
    const float* ew_p   = (const float*)d_in[12];
    const float* pos    = (const float*)d_in[13];

    const size_t NELEM = (size_t)MTOT * CDIM;   // 12,845,056
    float* ws    = (float*)d_ws;
    float* Qb    = ws;
    float* Gb    = ws + NELEM;
    float* Kb    = ws + 2 * NELEM;
    float* Vb    = ws + 3 * NELEM;
    float* QEb   = ws + 4 * NELEM;      // reused: Xbf, QE, PKV/PKM, ATT
    float* SMALL = ws + 5 * NELEM;
    float* ssum  = SMALL;               // 512
    float* ssq   = SMALL + 512;         // 512
    float* kmean = SMALL + 1024;        // 8192
    float* kvT   = SMALL + 9216;        // 524288 ([bh][e][d])
    float* invs  = SMALL + 533504;      // 512
    float* powr  = SMALL + 534016;      // 512
    float* achan = SMALL + 534528;      // 512
    float* bchan = SMALL + 535040;      // 512
    ushort* Wqg  = (ushort*)(SMALL + 535552);    // 524288 bf16
    ushort* Wkv  = (ushort*)(SMALL + 797696);    // 524288 bf16
    ushort* Wproj= (ushort*)(SMALL + 1059840);   // 262144 bf16

    ushort* Xbf  = (ushort*)QEb;        // x in bf16 (dead after kv gemm; conv3 overwrites)
    float* PKV   = QEb;                 // 7,340,032 floats (after QE dead)
    float* PKM   = QEb + 7340032;       // 114,688 floats
    float* ATTb  = QEb;                 // attn output (partials dead after kvreduce)
    ushort* PREbf= (ushort*)Kb;         // proj input bf16 (K dead after kvred2)

    hipMemsetAsync(SMALL, 0, (size_t)1024 * sizeof(float), stream);

    prep_kernel<<<1, 512, 0, stream>>>(scale_p, power_p, invs, powr);

    cvt_bf16_kernel<<<12544, 256, 0, stream>>>(x, Xbf, 3211264);
    cvt_bf16_kernel<<<512, 256, 0, stream>>>(qg_w, Wqg, 131072);
    cvt_bf16_kernel<<<512, 256, 0, stream>>>(kv_w, Wkv, 131072);
    cvt_bf16_kernel<<<256, 256, 0, stream>>>(proj_w, Wproj, 65536);

    dim3 ggrid(196, 8);
    mgemm<0><<<ggrid, 256, 0, stream>>>(Xbf, Wqg, Qb, Gb, nullptr, nullptr);
    mgemm<1><<<ggrid, 256, 0, stream>>>(Xbf, Wkv, Kb, Vb, pos, invs);

    dim3 cgrid(56, 32);
    conv3s_kernel<<<cgrid, 256, 0, stream>>>(Qb, enh_w, QEb, ssum, ssq);
    bnprep_kernel<<<1, 512, 0, stream>>>(ssum, ssq, bn_g, bn_b, achan, bchan);
    qfin_kernel<<<50176, 256, 0, stream>>>(Qb, QEb, achan, bchan, invs, ew_p);

    kvred2_kernel<<<dim3(64, 14), 256, 0, stream>>>(Kb, Vb, powr, PKV, PKM);
    kvreduce_kernel<<<2080, 256, 0, stream>>>(PKV, PKM, kvT, kmean);

    attn_mfma_kernel<<<dim3(64, 49), 256, 0, stream>>>(Qb, kvT, kmean, powr, ATTb);

    voutg2_kernel<<<cgrid, 256, 0, stream>>>(Vb, ATTb, Gb, dwc_w, dwc_b, PREbf);

    dim3 pgrid(196, 4);
    mgemm<2><<<pgrid, 256, 0, stream>>>(PREbf, Wproj, (float*)d_out, nullptr, proj_b, nullptr);
}

// Round 5
// 607.064 us; speedup vs baseline: 3.6715x; 1.0559x over previous
//
#include <hip/hip_runtime.h>
#include <hip/hip_bf16.h>
#include <math.h>

#define CDIM 512
#define NTOK 3136
#define BATCH 8
#define MTOT (BATCH*NTOK)   // 25088
#define NHEAD 8
#define DHEAD 64
#define HW 56

typedef __attribute__((ext_vector_type(8))) short short8;
typedef __attribute__((ext_vector_type(4))) float f32x4;

__device__ __forceinline__ ushort f2bf(float f) {
    union { float f; unsigned int u; } v; v.f = f;
    unsigned int u = v.u + 0x7FFFu + ((v.u >> 16) & 1u);
    return (ushort)(u >> 16);
}

__device__ __forceinline__ void gload_lds16(const void* g, void* lds) {
    __builtin_amdgcn_global_load_lds((const __attribute__((address_space(1))) void*)g,
                                     (__attribute__((address_space(3))) void*)lds,
                                     16, 0, 0);
}

// ---------------- prep: per-channel inv_scale and power ----------------
__global__ void prep_kernel(const float* __restrict__ scale_p,
                            const float* __restrict__ power_p,
                            float* __restrict__ inv_scale,
                            float* __restrict__ power) {
    int c = threadIdx.x;
    if (c < CDIM) {
        float s = log1pf(expf(scale_p[c]));        // softplus
        inv_scale[c] = 1.0f / s;
        power[c] = 1.0f + 4.0f / (1.0f + expf(-power_p[c]));  // 1+ALPHA*sigmoid
    }
}

// ---------------- fp32 -> bf16 conversion (vectorized) ----------------
__global__ __launch_bounds__(256) void cvt_bf16_kernel(const float* __restrict__ src,
                                                       ushort* __restrict__ dst, int n4) {
    int i = blockIdx.x * 256 + threadIdx.x;
    if (i < n4) {
        float4 f = ((const float4*)src)[i];
        ushort4 o;
        o.x = f2bf(f.x); o.y = f2bf(f.y); o.z = f2bf(f.z); o.w = f2bf(f.w);
        ((ushort4*)dst)[i] = o;
    }
}

// ---------------- bf16 MFMA GEMM: out[m,o] = sum_c A[m,c]*B[o,c] ----------------
template<int EPI>
__global__ __launch_bounds__(256) void mgemm(const ushort* __restrict__ A,
                                             const ushort* __restrict__ B,
                                             float* __restrict__ out0,
                                             float* __restrict__ out1,
                                             const float* __restrict__ aux0,
                                             const float* __restrict__ aux1) {
    __shared__ ushort At[128 * 64];
    __shared__ ushort Bt[128 * 64];
    const int t = threadIdx.x;
    const int w = t >> 6, l = t & 63;
    const int m0 = blockIdx.x * 128, o0 = blockIdx.y * 128;
    const int wr = w >> 1, wc = w & 1;
    f32x4 acc[4][4] = {};
    const int r8 = l >> 3, sl = l & 7;
    const int ss = sl ^ r8;            // swizzled source slot (involution)

    for (int ks = 0; ks < 8; ++ks) {
        const int k0 = ks * 64;
        #pragma unroll
        for (int c = 0; c < 4; ++c) {
            int rc = (w * 4 + c) * 8 + r8;     // tile row this lane stages
            gload_lds16(A + (size_t)(m0 + rc) * CDIM + k0 + ss * 8, At + (w * 4 + c) * 512);
            gload_lds16(B + (size_t)(o0 + rc) * CDIM + k0 + ss * 8, Bt + (w * 4 + c) * 512);
        }
        __syncthreads();
        #pragma unroll
        for (int kk = 0; kk < 2; ++kk) {
            short8 af[4], bfr[4];
            const int sbase = kk * 4 + (l >> 4);
            #pragma unroll
            for (int i = 0; i < 4; ++i) {
                int row = wr * 64 + i * 16 + (l & 15);
                af[i] = *(const short8*)&At[row * 64 + ((sbase ^ (row & 7)) * 8)];
                int rowb = wc * 64 + i * 16 + (l & 15);
                bfr[i] = *(const short8*)&Bt[rowb * 64 + ((sbase ^ (rowb & 7)) * 8)];
            }
            #pragma unroll
            for (int i = 0; i < 4; ++i)
                #pragma unroll
                for (int j = 0; j < 4; ++j)
                    acc[i][j] = __builtin_amdgcn_mfma_f32_16x16x32_bf16(af[i], bfr[j], acc[i][j], 0, 0, 0);
        }
        __syncthreads();
    }
    #pragma unroll
    for (int i = 0; i < 4; ++i) {
        #pragma unroll
        for (int rr = 0; rr < 4; ++rr) {
            int m = m0 + wr * 64 + i * 16 + (l >> 4) * 4 + rr;
            size_t mrow = (size_t)m * CDIM;
            #pragma unroll
            for (int j = 0; j < 4; ++j) {
                int o = o0 + wc * 64 + j * 16 + (l & 15);
                float v = acc[i][j][rr];
                if (EPI == 0) {
                    if (o < CDIM) out0[mrow + o] = v;
                    else          out1[mrow + o - CDIM] = v;
                } else if (EPI == 1) {
                    if (o < CDIM) {
                        int n = m % NTOK;
                        out0[mrow + o] = (v + aux0[(size_t)n * CDIM + o]) * aux1[o];
                    } else {
                        out1[mrow + o - CDIM] = v;
                    }
                } else {
                    out0[mrow + o] = v + aux0[o];
                }
            }
        }
    }
}

// ---------------- fused 3x3 depthwise conv + BN-stats accumulation ----------------
__global__ __launch_bounds__(256) void conv3s_kernel(const float* __restrict__ Q,
                                                     const float* __restrict__ enh_w,
                                                     float* __restrict__ QE,
                                                     float* __restrict__ ssum,
                                                     float* __restrict__ ssq) {
    const int t = threadIdx.x;
    const int c0 = t * 2;
    const int xpos = blockIdx.x;
    const int byc = blockIdx.y;
    const int b = byc >> 2, yc = byc & 3;
    const int y0 = yc * 14;

    float wgt[9][2];
    #pragma unroll
    for (int tap = 0; tap < 9; ++tap) {
        wgt[tap][0] = enh_w[c0 * 9 + tap];
        wgt[tap][1] = enh_w[(c0 + 1) * 9 + tap];
    }
    const size_t base = (size_t)b * NTOK * CDIM + c0;

    float2 win[3][3];
    auto ldrow = [&](int yy, float2* dst) {
        #pragma unroll
        for (int dx = 0; dx < 3; ++dx) {
            int xx = xpos + dx - 1;
            bool ok = (yy >= 0 && yy < HW && xx >= 0 && xx < HW);
            dst[dx] = ok ? *(const float2*)(Q + base + ((size_t)(yy * HW + xx) << 9))
                         : make_float2(0.f, 0.f);
        }
    };
    ldrow(y0 - 1, win[0]);
    ldrow(y0,     win[1]);

    float s1a = 0.f, s2a = 0.f, s1b = 0.f, s2b = 0.f;
    #pragma unroll
    for (int i = 0; i < 14; ++i) {
        int y = y0 + i;
        ldrow(y + 1, win[(i + 2) % 3]);
        float a0 = 0.f, a1 = 0.f;
        #pragma unroll
        for (int dy = 0; dy < 3; ++dy) {
            float2* row = win[(i + dy) % 3];
            #pragma unroll
            for (int dx = 0; dx < 3; ++dx) {
                a0 = fmaf(row[dx].x, wgt[dy * 3 + dx][0], a0);
                a1 = fmaf(row[dx].y, wgt[dy * 3 + dx][1], a1);
            }
        }
        *(float2*)(QE + base + ((size_t)(y * HW + xpos) << 9)) = make_float2(a0, a1);
        s1a += a0; s2a += a0 * a0;
        s1b += a1; s2b += a1 * a1;
    }
    atomicAdd(&ssum[c0], s1a);     atomicAdd(&ssq[c0], s2a);
    atomicAdd(&ssum[c0 + 1], s1b); atomicAdd(&ssq[c0 + 1], s2b);
}

__global__ void bnprep_kernel(const float* __restrict__ ssum, const float* __restrict__ ssq,
                              const float* __restrict__ bn_g, const float* __restrict__ bn_b,
                              float* __restrict__ achan, float* __restrict__ bchan) {
    int c = threadIdx.x;
    if (c < CDIM) {
        const float invM = 1.0f / (float)MTOT;
        float mean = ssum[c] * invM;
        float var  = ssq[c] * invM - mean * mean;
        float a = bn_g[c] * rsqrtf(var + 1e-5f);
        achan[c] = a;
        bchan[c] = bn_b[c] - mean * a;
    }
}

// ---------------- finalize q: Q = (Q + ew*relu(a*QE+b)) * inv_scale ----------------
__global__ __launch_bounds__(256) void qfin_kernel(float* __restrict__ Q,
                                                   const float* __restrict__ QE,
                                                   const float* __restrict__ achan,
                                                   const float* __restrict__ bchan,
                                                   const float* __restrict__ inv_scale,
                                                   const float* __restrict__ ewp) {
    int gid = blockIdx.x * 256 + threadIdx.x;
    int c = gid & (CDIM - 1);
    float ew = ewp[0];
    float e = fmaxf(fmaf(achan[c], QE[gid], bchan[c]), 0.f);
    Q[gid] = fmaf(ew, e, Q[gid]) * inv_scale[c];
}

// ---------------- kvred v3: MFMA. C[d][e] = sum_n KF[n][d] V[n][e] per bh ----------------
// grid (64 bh, 14 chunks), 224 rows = 7 tiles of 32. Output PKV[(chunk*64+bh)][e=65][d=128]
// (col e=64 = kmean raw sums via ones-row in B).
__global__ __launch_bounds__(256) void kvred3_kernel(const float* __restrict__ K,
                                                     const float* __restrict__ V,
                                                     const float* __restrict__ power,
                                                     float* __restrict__ PKV) {
    const int bh = blockIdx.x, chunk = blockIdx.y;
    const int b = bh >> 3, head = bh & 7;
    const int t = threadIdx.x;
    const int w = t >> 6, l = t & 63;
    __shared__ float Ks[32 * 64];
    __shared__ float Vs[32 * 64];
    __shared__ ushort KFT[128 * 40];   // [d][n] bf16, row stride 40 (80B) breaks conflicts
    __shared__ ushort VT[80 * 40];     // [e][n] bf16; row 64 = ones, 65..79 = 0

    // const rows of VT (written once; barrier below covers visibility)
    for (int idx = t; idx < 16 * 40; idx += 256)
        VT[64 * 40 + idx] = (idx < 40) ? (ushort)0x3F80 : (ushort)0;

    const int dkf = t >> 1;            // 0..127
    const int nh  = (t & 1) * 16;      // n-half for KFT build
    const float p_kf = power[head * 64 + (dkf & 63)];
    const bool neg_kf = dkf >= 64;
    const int ev = t >> 2;             // 0..63
    const int nq = (t & 3) * 8;        // n-quarter for VT build

    f32x4 acc[2][5] = {};
    const int nbase = b * NTOK + chunk * 224;
    for (int tile = 0; tile < 7; ++tile) {
        const int n0 = nbase + tile * 32;
        #pragma unroll
        for (int i = 0; i < 2; ++i) {
            int f = t + i * 256;       // 0..511; lds byte off = f*16 (linear in lane)
            size_t g = (size_t)(n0 + (f >> 4)) * CDIM + head * 64 + (f & 15) * 4;
            gload_lds16(K + g, Ks + f * 4);
            gload_lds16(V + g, Vs + f * 4);
        }
        __syncthreads();
        // build KFT: thread handles d=dkf, n in [nh, nh+16)
        {
            short8 pk[2];
            #pragma unroll
            for (int h = 0; h < 2; ++h) {
                #pragma unroll
                for (int n = 0; n < 8; ++n) {
                    float kraw = Ks[(nh + h * 8 + n) * 64 + (dkf & 63)];
                    float kx = neg_kf ? -kraw : kraw;
                    pk[h][n] = (kx > 0.f) ? (short)f2bf(__powf(kx, p_kf)) : (short)0;
                }
            }
            *(short8*)&KFT[dkf * 40 + nh]     = pk[0];
            *(short8*)&KFT[dkf * 40 + nh + 8] = pk[1];
        }
        // build VT: thread handles e=ev, n in [nq, nq+8)
        {
            short8 pv;
            #pragma unroll
            for (int n = 0; n < 8; ++n)
                pv[n] = (short)f2bf(Vs[(nq + n) * 64 + ev]);
            *(short8*)&VT[ev * 40 + nq] = pv;
        }
        __syncthreads();
        // MFMA: wave w owns d-rows [32w, 32w+32); one K=32 step
        {
            short8 af[2], bfr[5];
            const int ksl = (l >> 4) * 8;
            #pragma unroll
            for (int i = 0; i < 2; ++i)
                af[i] = *(const short8*)&KFT[(w * 32 + i * 16 + (l & 15)) * 40 + ksl];
            #pragma unroll
            for (int j = 0; j < 5; ++j)
                bfr[j] = *(const short8*)&VT[(j * 16 + (l & 15)) * 40 + ksl];
            #pragma unroll
            for (int i = 0; i < 2; ++i)
                #pragma unroll
                for (int j = 0; j < 5; ++j)
                    acc[i][j] = __builtin_amdgcn_mfma_f32_16x16x32_bf16(af[i], bfr[j], acc[i][j], 0, 0, 0);
        }
        __syncthreads();
    }
    // write partials: C row = d, col = e; lane holds 4 consecutive d at fixed e
    size_t base = ((size_t)(chunk * 64 + bh)) * 8320;   // 65*128
    #pragma unroll
    for (int i = 0; i < 2; ++i) {
        int d0 = w * 32 + i * 16 + (l >> 4) * 4;
        #pragma unroll
        for (int j = 0; j < 5; ++j) {
            int e = j * 16 + (l & 15);
            if (j < 4 || e == 64)
                *(f32x4*)(PKV + base + (size_t)e * 128 + d0) = acc[i][j];
        }
    }
}

// reduce partials: kvT[bh][e=64][d=128], kmean[bh][128]
__global__ __launch_bounds__(256) void kvreduce_kernel(const float* __restrict__ PKV,
                                                       float* __restrict__ kvT,
                                                       float* __restrict__ kmean) {
    int gid = blockIdx.x * 256 + threadIdx.x;   // 0..532479 = 64*65*128
    const float inv_n = 1.0f / (float)NTOK;
    float s = 0.f;
    #pragma unroll
    for (int c = 0; c < 14; ++c) s += PKV[(size_t)c * 532480 + gid];
    s *= inv_n;
    int bh = gid / 8320;
    int r  = gid - bh * 8320;
    int e = r >> 7, d = r & 127;
    if (e < 64) kvT[(size_t)bh * 8192 + e * 128 + d] = s;
    else        kmean[bh * 128 + d] = s;
}

// ---------------- attention apply via MFMA: [64 tok][128] x [128][80] ----------------
__global__ __launch_bounds__(256) void attn_mfma_kernel(const float* __restrict__ Q,
                                                        const float* __restrict__ kvT,
                                                        const float* __restrict__ kmean,
                                                        const float* __restrict__ power,
                                                        float* __restrict__ ATT) {
    __shared__ ushort QF[64 * 128];
    __shared__ ushort BT[80 * 128];
    const int bh = blockIdx.x, tb = blockIdx.y;
    const int b = bh >> 3, head = bh & 7;
    const int t = threadIdx.x;
    const int w = t >> 6, l = t & 63;

    const int c = l;
    const float p = power[head * 64 + c];
    #pragma unroll
    for (int i = 0; i < 16; ++i) {
        int tok = i * 4 + w;
        float q = Q[((size_t)(b * NTOK + tb * 64 + tok)) * CDIM + head * 64 + c];
        float ax = fabsf(q);
        float tp = ax > 0.f ? __powf(ax, p) : 0.f;
        float qp = q > 0.f ? tp : 0.f;
        float qn = q < 0.f ? tp : 0.f;
        int sw = tok & 7;
        QF[tok * 128 + (((c >> 3) ^ sw) * 8) + (c & 7)]       = f2bf(qp);
        QF[tok * 128 + ((((c >> 3) + 8) ^ sw) * 8) + (c & 7)] = f2bf(qn);
    }
    #pragma unroll
    for (int i = 0; i < 5; ++i) {
        int qc = i * 256 + t;
        int row = qc >> 4, s = qc & 15;
        int ls = s ^ (row & 7);
        int d0 = ls * 8;
        short8 ov;
        if (row < 64) {
            int dsel = (row >= 32) ? (d0 ^ 64) : d0;
            const float* src = kvT + (size_t)bh * 8192 + row * 128 + dsel;
            #pragma unroll
            for (int e = 0; e < 8; ++e) ov[e] = (short)f2bf(src[e]);
        } else if (row == 64) {
            const float* src = kmean + bh * 128 + d0;
            #pragma unroll
            for (int e = 0; e < 8; ++e) ov[e] = (short)f2bf(src[e]);
        } else if (row == 65) {
            const float* src = kmean + bh * 128 + (d0 ^ 64);
            #pragma unroll
            for (int e = 0; e < 8; ++e) ov[e] = (short)f2bf(src[e]);
        } else {
            #pragma unroll
            for (int e = 0; e < 8; ++e) ov[e] = 0;
        }
        *(short8*)&BT[row * 128 + s * 8] = ov;
    }
    __syncthreads();

    f32x4 acc[5] = {};
    #pragma unroll
    for (int kk = 0; kk < 4; ++kk) {
        int sbase = kk * 4 + (l >> 4);
        int rowa = w * 16 + (l & 15);
        short8 af = *(const short8*)&QF[rowa * 128 + ((sbase ^ (rowa & 7)) * 8)];
        #pragma unroll
        for (int j = 0; j < 5; ++j) {
            int rowb = j * 16 + (l & 15);
            short8 bf = *(const short8*)&BT[rowb * 128 + ((sbase ^ (rowb & 7)) * 8)];
            acc[j] = __builtin_amdgcn_mfma_f32_16x16x32_bf16(af, bf, acc[j], 0, 0, 0);
        }
    }
    #pragma unroll
    for (int rr = 0; rr < 4; ++rr) {
        float ssim = __shfl(acc[4][rr], (l & 48));
        float sopp = __shfl(acc[4][rr], (l & 48) + 1);
        float zs = 1.f / (ssim + 1e-6f);
        float zo = 1.f / (sopp + 1e-6f);
        int tok = tb * 64 + w * 16 + (l >> 4) * 4 + rr;
        size_t base = ((size_t)(b * NTOK + tok)) * CDIM + head * 64;
        #pragma unroll
        for (int j = 0; j < 4; ++j) {
            int e = j * 16 + (l & 15);
            ATT[base + e] = acc[j][rr] * (j < 2 ? zs : zo);
        }
    }
}

// ---------------- v2 5x5 depthwise conv + gate, register-rolling window ----------------
__global__ __launch_bounds__(256) void voutg2_kernel(const float* __restrict__ V,
                                                     const float* __restrict__ ATT,
                                                     const float* __restrict__ G,
                                                     const float* __restrict__ dwc_w,
                                                     const float* __restrict__ dwc_b,
                                                     ushort* __restrict__ PRE) {
    const int t = threadIdx.x;
    const int c0 = t * 2;
    const int xpos = blockIdx.x;
    const int byc = blockIdx.y;
    const int b = byc >> 2, yc = byc & 3;
    const int y0 = yc * 14;
    const int dch = c0 & 63;

    float wgt[25][2];
    #pragma unroll
    for (int tap = 0; tap < 25; ++tap) {
        wgt[tap][0] = dwc_w[dch * 25 + tap];
        wgt[tap][1] = dwc_w[(dch + 1) * 25 + tap];
    }
    const float bias0 = dwc_b[dch], bias1 = dwc_b[dch + 1];
    const size_t base = (size_t)b * NTOK * CDIM + c0;

    float2 win[5][5];
    auto ldrow = [&](int yy, float2* dst) {
        #pragma unroll
        for (int dx = 0; dx < 5; ++dx) {
            int xx = xpos + dx - 2;
            bool ok = (yy >= 0 && yy < HW && xx >= 0 && xx < HW);
            dst[dx] = ok ? *(const float2*)(V + base + ((size_t)(yy * HW + xx) << 9))
                         : make_float2(0.f, 0.f);
        }
    };
    ldrow(y0 - 2, win[0]);
    ldrow(y0 - 1, win[1]);
    ldrow(y0,     win[2]);
    ldrow(y0 + 1, win[3]);

    #pragma unroll
    for (int i = 0; i < 14; ++i) {
        int y = y0 + i;
        ldrow(y + 2, win[(i + 4) % 5]);
        float a0 = bias0, a1 = bias1;
        #pragma unroll
        for (int dy = 0; dy < 5; ++dy) {
            float2* row = win[(i + dy) % 5];
            #pragma unroll
            for (int dx = 0; dx < 5; ++dx) {
                a0 = fmaf(row[dx].x, wgt[dy * 5 + dx][0], a0);
                a1 = fmaf(row[dx].y, wgt[dy * 5 + dx][1], a1);
            }
        }
        size_t oidx = base + ((size_t)(y * HW + xpos) << 9);
        float2 att = *(const float2*)(ATT + oidx);
        float2 g   = *(const float2*)(G + oidx);
        ushort2 o;
        o.x = f2bf((att.x + a0) * g.x);
        o.y = f2bf((att.y + a1) * g.y);
        *(ushort2*)(PRE + oidx) = o;
    }
}

extern "C" void kernel_launch(void* const* d_in, const int* in_sizes, int n_in,
                              void* d_out, int out_size, void* d_ws, size_t ws_size,
                              hipStream_t stream) {
    const float* x      = (const float*)d_in[0];
    const float* qg_w   = (const float*)d_in[1];
    const float* kv_w   = (const float*)d_in[2];
    const float* proj_w = (const float*)d_in[3];
    const float* proj_b = (const float*)d_in[4];
    const float* dwc_w  = (const float*)d_in[5];
    const float* dwc_b  = (const float*)d_in[6];
    const float* power_p= (const float*)d_in[7];
    const float* scale_p= (const float*)d_in[8];
    const float* enh_w  = (const float*)d_in[9];
    const float* bn_g   = (const float*)d_in[10];
    const float* bn_b   = (const float*)d_in[11];
    const float* ew_p   = (const float*)d_in[12];
    const float* pos    = (const float*)d_in[13];

    const size_t NELEM = (size_t)MTOT * CDIM;   // 12,845,056
    float* ws    = (float*)d_ws;
    float* Qb    = ws;
    float* Gb    = ws + NELEM;
    float* Kb    = ws + 2 * NELEM;
    float* Vb    = ws + 3 * NELEM;
    float* QEb   = ws + 4 * NELEM;      // reused: Xbf, QE, PKV, ATT
    float* SMALL = ws + 5 * NELEM;
    float* ssum  = SMALL;               // 512
    float* ssq   = SMALL + 512;         // 512
    float* kmean = SMALL + 1024;        // 8192
    float* kvT   = SMALL + 9216;        // 524288 ([bh][e][d])
    float* invs  = SMALL + 533504;      // 512
    float* powr  = SMALL + 534016;      // 512
    float* achan = SMALL + 534528;      // 512
    float* bchan = SMALL + 535040;      // 512
    ushort* Wqg  = (ushort*)(SMALL + 535552);    // 524288 bf16
    ushort* Wkv  = (ushort*)(SMALL + 797696);    // 524288 bf16
    ushort* Wproj= (ushort*)(SMALL + 1059840);   // 262144 bf16

    ushort* Xbf  = (ushort*)QEb;        // x in bf16 (dead after kv gemm; conv3 overwrites)
    float* PKV   = QEb;                 // 14*532480 = 7,454,720 floats (QE dead after qfin)
    float* ATTb  = QEb;                 // attn output (partials dead after kvreduce)
    ushort* PREbf= (ushort*)Kb;         // proj input bf16 (K dead after kvred3)

    hipMemsetAsync(SMALL, 0, (size_t)1024 * sizeof(float), stream);

    prep_kernel<<<1, 512, 0, stream>>>(scale_p, power_p, invs, powr);

    cvt_bf16_kernel<<<12544, 256, 0, stream>>>(x, Xbf, 3211264);
    cvt_bf16_kernel<<<512, 256, 0, stream>>>(qg_w, Wqg, 131072);
    cvt_bf16_kernel<<<512, 256, 0, stream>>>(kv_w, Wkv, 131072);
    cvt_bf16_kernel<<<256, 256, 0, stream>>>(proj_w, Wproj, 65536);

    dim3 ggrid(196, 8);
    mgemm<0><<<ggrid, 256, 0, stream>>>(Xbf, Wqg, Qb, Gb, nullptr, nullptr);
    mgemm<1><<<ggrid, 256, 0, stream>>>(Xbf, Wkv, Kb, Vb, pos, invs);

    dim3 cgrid(56, 32);
    conv3s_kernel<<<cgrid, 256, 0, stream>>>(Qb, enh_w, QEb, ssum, ssq);
    bnprep_kernel<<<1, 512, 0, stream>>>(ssum, ssq, bn_g, bn_b, achan, bchan);
    qfin_kernel<<<50176, 256, 0, stream>>>(Qb, QEb, achan, bchan, invs, ew_p);

    kvred3_kernel<<<dim3(64, 14), 256, 0, stream>>>(Kb, Vb, powr, PKV);
    kvreduce_kernel<<<2080, 256, 0, stream>>>(PKV, kvT, kmean);

    attn_mfma_kernel<<<dim3(64, 49), 256, 0, stream>>>(Qb, kvT, kmean, powr, ATTb);

    voutg2_kernel<<<cgrid, 256, 0, stream>>>(Vb, ATTb, Gb, dwc_w, dwc_b, PREbf);

    dim3 pgrid(196, 4);
    mgemm<2><<<pgrid, 256, 0, stream>>>(PREbf, Wproj, (float*)d_out, nullptr, proj_b, nullptr);
}

// Round 6
// 558.248 us; speedup vs baseline: 3.9926x; 1.0874x over previous
//
#include <hip/hip_runtime.h>
#include <hip/hip_bf16.h>
#include <math.h>

#define CDIM 512
#define NTOK 3136
#define BATCH 8
#define MTOT (BATCH*NTOK)   // 25088
#define NHEAD 8
#define DHEAD 64
#define HW 56

typedef __attribute__((ext_vector_type(8))) short short8;
typedef __attribute__((ext_vector_type(4))) float f32x4;

__device__ __forceinline__ ushort f2bf(float f) {
    union { float f; unsigned int u; } v; v.f = f;
    unsigned int u = v.u + 0x7FFFu + ((v.u >> 16) & 1u);
    return (ushort)(u >> 16);
}
__device__ __forceinline__ float bf2f(ushort u) {
    union { unsigned int u; float f; } v; v.u = ((unsigned int)u) << 16;
    return v.f;
}

__device__ __forceinline__ void gload_lds16(const void* g, void* lds) {
    __builtin_amdgcn_global_load_lds((const __attribute__((address_space(1))) void*)g,
                                     (__attribute__((address_space(3))) void*)lds,
                                     16, 0, 0);
}

// ---------------- prep: per-channel inv_scale and power ----------------
__global__ void prep_kernel(const float* __restrict__ scale_p,
                            const float* __restrict__ power_p,
                            float* __restrict__ inv_scale,
                            float* __restrict__ power) {
    int c = threadIdx.x;
    if (c < CDIM) {
        float s = log1pf(expf(scale_p[c]));        // softplus
        inv_scale[c] = 1.0f / s;
        power[c] = 1.0f + 4.0f / (1.0f + expf(-power_p[c]));  // 1+ALPHA*sigmoid
    }
}

// ---------------- fp32 -> bf16 conversion (vectorized) ----------------
__global__ __launch_bounds__(256) void cvt_bf16_kernel(const float* __restrict__ src,
                                                       ushort* __restrict__ dst, int n4) {
    int i = blockIdx.x * 256 + threadIdx.x;
    if (i < n4) {
        float4 f = ((const float4*)src)[i];
        ushort4 o;
        o.x = f2bf(f.x); o.y = f2bf(f.y); o.z = f2bf(f.z); o.w = f2bf(f.w);
        ((ushort4*)dst)[i] = o;
    }
}

// ---------------- bf16 MFMA GEMM: out[m,o] = sum_c A[m,c]*B[o,c] ----------------
// EPI 0: qg  -> out0=Q fp32 (o<512), out1=G fp32
// EPI 1: kv  -> out0=KFbf ushort [m][8h][128d] (pos|neg of ((acc+pos_enc)*invs)^p),
//               out1=Vbf ushort [m][512]; aux0=pos_enc, aux1=invs, aux2=power
// EPI 2: proj-> out0=fp32 acc+proj_b; aux0=proj_b
template<int EPI>
__global__ __launch_bounds__(256) void mgemm(const ushort* __restrict__ A,
                                             const ushort* __restrict__ B,
                                             void* __restrict__ out0v,
                                             void* __restrict__ out1v,
                                             const float* __restrict__ aux0,
                                             const float* __restrict__ aux1,
                                             const float* __restrict__ aux2) {
    __shared__ ushort At[128 * 64];
    __shared__ ushort Bt[128 * 64];
    const int t = threadIdx.x;
    const int w = t >> 6, l = t & 63;
    const int m0 = blockIdx.x * 128, o0 = blockIdx.y * 128;
    const int wr = w >> 1, wc = w & 1;
    f32x4 acc[4][4] = {};
    const int r8 = l >> 3, sl = l & 7;
    const int ss = sl ^ r8;            // swizzled source slot (involution)

    for (int ks = 0; ks < 8; ++ks) {
        const int k0 = ks * 64;
        #pragma unroll
        for (int c = 0; c < 4; ++c) {
            int rc = (w * 4 + c) * 8 + r8;     // tile row this lane stages
            gload_lds16(A + (size_t)(m0 + rc) * CDIM + k0 + ss * 8, At + (w * 4 + c) * 512);
            gload_lds16(B + (size_t)(o0 + rc) * CDIM + k0 + ss * 8, Bt + (w * 4 + c) * 512);
        }
        __syncthreads();
        #pragma unroll
        for (int kk = 0; kk < 2; ++kk) {
            short8 af[4], bfr[4];
            const int sbase = kk * 4 + (l >> 4);
            #pragma unroll
            for (int i = 0; i < 4; ++i) {
                int row = wr * 64 + i * 16 + (l & 15);
                af[i] = *(const short8*)&At[row * 64 + ((sbase ^ (row & 7)) * 8)];
                int rowb = wc * 64 + i * 16 + (l & 15);
                bfr[i] = *(const short8*)&Bt[rowb * 64 + ((sbase ^ (rowb & 7)) * 8)];
            }
            #pragma unroll
            for (int i = 0; i < 4; ++i)
                #pragma unroll
                for (int j = 0; j < 4; ++j)
                    acc[i][j] = __builtin_amdgcn_mfma_f32_16x16x32_bf16(af[i], bfr[j], acc[i][j], 0, 0, 0);
        }
        __syncthreads();
    }
    #pragma unroll
    for (int i = 0; i < 4; ++i) {
        #pragma unroll
        for (int rr = 0; rr < 4; ++rr) {
            int m = m0 + wr * 64 + i * 16 + (l >> 4) * 4 + rr;
            size_t mrow = (size_t)m * CDIM;
            #pragma unroll
            for (int j = 0; j < 4; ++j) {
                int o = o0 + wc * 64 + j * 16 + (l & 15);
                float v = acc[i][j][rr];
                if (EPI == 0) {
                    if (o < CDIM) ((float*)out0v)[mrow + o] = v;
                    else          ((float*)out1v)[mrow + o - CDIM] = v;
                } else if (EPI == 1) {
                    if (o < CDIM) {
                        int n = m % NTOK;
                        float kx = (v + aux0[(size_t)n * CDIM + o]) * aux1[o];
                        float tp = __powf(fabsf(kx), aux2[o]);
                        ushort kfp = kx > 0.f ? f2bf(tp) : (ushort)0;
                        ushort kfn = kx < 0.f ? f2bf(tp) : (ushort)0;
                        ushort* dst = (ushort*)out0v + ((size_t)m * 8 + (o >> 6)) * 128 + (o & 63);
                        dst[0] = kfp;
                        dst[64] = kfn;
                    } else {
                        ((ushort*)out1v)[mrow + o - CDIM] = f2bf(v);
                    }
                } else {
                    ((float*)out0v)[mrow + o] = v + aux0[o];
                }
            }
        }
    }
}

// ---------------- fused 3x3 depthwise conv + BN-stats accumulation ----------------
__global__ __launch_bounds__(256) void conv3s_kernel(const float* __restrict__ Q,
                                                     const float* __restrict__ enh_w,
                                                     float* __restrict__ QE,
                                                     float* __restrict__ ssum,
                                                     float* __restrict__ ssq) {
    const int t = threadIdx.x;
    const int c0 = t * 2;
    const int xpos = blockIdx.x;
    const int byc = blockIdx.y;
    const int b = byc >> 2, yc = byc & 3;
    const int y0 = yc * 14;

    float wgt[9][2];
    #pragma unroll
    for (int tap = 0; tap < 9; ++tap) {
        wgt[tap][0] = enh_w[c0 * 9 + tap];
        wgt[tap][1] = enh_w[(c0 + 1) * 9 + tap];
    }
    const size_t base = (size_t)b * NTOK * CDIM + c0;

    float2 win[3][3];
    auto ldrow = [&](int yy, float2* dst) {
        #pragma unroll
        for (int dx = 0; dx < 3; ++dx) {
            int xx = xpos + dx - 1;
            bool ok = (yy >= 0 && yy < HW && xx >= 0 && xx < HW);
            dst[dx] = ok ? *(const float2*)(Q + base + ((size_t)(yy * HW + xx) << 9))
                         : make_float2(0.f, 0.f);
        }
    };
    ldrow(y0 - 1, win[0]);
    ldrow(y0,     win[1]);

    float s1a = 0.f, s2a = 0.f, s1b = 0.f, s2b = 0.f;
    #pragma unroll
    for (int i = 0; i < 14; ++i) {
        int y = y0 + i;
        ldrow(y + 1, win[(i + 2) % 3]);
        float a0 = 0.f, a1 = 0.f;
        #pragma unroll
        for (int dy = 0; dy < 3; ++dy) {
            float2* row = win[(i + dy) % 3];
            #pragma unroll
            for (int dx = 0; dx < 3; ++dx) {
                a0 = fmaf(row[dx].x, wgt[dy * 3 + dx][0], a0);
                a1 = fmaf(row[dx].y, wgt[dy * 3 + dx][1], a1);
            }
        }
        *(float2*)(QE + base + ((size_t)(y * HW + xpos) << 9)) = make_float2(a0, a1);
        s1a += a0; s2a += a0 * a0;
        s1b += a1; s2b += a1 * a1;
    }
    atomicAdd(&ssum[c0], s1a);     atomicAdd(&ssq[c0], s2a);
    atomicAdd(&ssum[c0 + 1], s1b); atomicAdd(&ssq[c0 + 1], s2b);
}

__global__ void bnprep_kernel(const float* __restrict__ ssum, const float* __restrict__ ssq,
                              const float* __restrict__ bn_g, const float* __restrict__ bn_b,
                              float* __restrict__ achan, float* __restrict__ bchan) {
    int c = threadIdx.x;
    if (c < CDIM) {
        const float invM = 1.0f / (float)MTOT;
        float mean = ssum[c] * invM;
        float var  = ssq[c] * invM - mean * mean;
        float a = bn_g[c] * rsqrtf(var + 1e-5f);
        achan[c] = a;
        bchan[c] = bn_b[c] - mean * a;
    }
}

// ---------------- finalize q: Q = (Q + ew*relu(a*QE+b)) * inv_scale ----------------
__global__ __launch_bounds__(256) void qfin_kernel(float* __restrict__ Q,
                                                   const float* __restrict__ QE,
                                                   const float* __restrict__ achan,
                                                   const float* __restrict__ bchan,
                                                   const float* __restrict__ inv_scale,
                                                   const float* __restrict__ ewp) {
    int gid = blockIdx.x * 256 + threadIdx.x;
    int c = gid & (CDIM - 1);
    float ew = ewp[0];
    float e = fmaxf(fmaf(achan[c], QE[gid], bchan[c]), 0.f);
    Q[gid] = fmaf(ew, e, Q[gid]) * inv_scale[c];
}

// ---------------- kvred v4: zero-LDS register MFMA GEMM over precomputed KFbf/Vbf ----------
// grid (64 bh, 14 chunks), 256 thr. Wave w owns d-rows [32w,32w+32).
// Fragments loaded straight from HBM (16-lane groups read 32B-contiguous).
// Output PKV[(chunk*64+bh)][e=65][d=128]; col 64 = kmean sums via const ones column.
__global__ __launch_bounds__(256) void kvred4_kernel(const ushort* __restrict__ KF,
                                                     const ushort* __restrict__ Vbf,
                                                     float* __restrict__ PKV) {
    const int bh = blockIdx.x, chunk = blockIdx.y;
    const int b = bh >> 3, head = bh & 7;
    const int t = threadIdx.x;
    const int w = t >> 6, l = t & 63;
    const int lr = l & 15;          // fragment lane-row
    const int ns = (l >> 4) * 8;    // n-slice base within 32-tile

    const int nbase = b * NTOK + chunk * 224;
    const ushort* kf0 = KF  + ((size_t)(nbase + ns)) * 1024 + head * 128 + (w * 32 + lr);
    const ushort* vb0 = Vbf + ((size_t)(nbase + ns)) * 512  + head * 64  + lr;

    short8 ones;
    #pragma unroll
    for (int j = 0; j < 8; ++j) ones[j] = (lr == 0) ? (short)0x3F80 : (short)0;

    f32x4 acc[2][5] = {};
    for (int tile = 0; tile < 7; ++tile) {
        union { uint u[4]; short8 s; } ua[2], ub[4];
        #pragma unroll
        for (int i = 0; i < 2; ++i) {
            #pragma unroll
            for (int j = 0; j < 4; ++j) {
                uint lo = kf0[i * 16 + (size_t)(2 * j) * 1024];
                uint hi = kf0[i * 16 + (size_t)(2 * j + 1) * 1024];
                ua[i].u[j] = lo | (hi << 16);
            }
        }
        #pragma unroll
        for (int j5 = 0; j5 < 4; ++j5) {
            #pragma unroll
            for (int j = 0; j < 4; ++j) {
                uint lo = vb0[j5 * 16 + (size_t)(2 * j) * 512];
                uint hi = vb0[j5 * 16 + (size_t)(2 * j + 1) * 512];
                ub[j5].u[j] = lo | (hi << 16);
            }
        }
        #pragma unroll
        for (int i = 0; i < 2; ++i) {
            #pragma unroll
            for (int j5 = 0; j5 < 4; ++j5)
                acc[i][j5] = __builtin_amdgcn_mfma_f32_16x16x32_bf16(ua[i].s, ub[j5].s, acc[i][j5], 0, 0, 0);
            acc[i][4] = __builtin_amdgcn_mfma_f32_16x16x32_bf16(ua[i].s, ones, acc[i][4], 0, 0, 0);
        }
        kf0 += (size_t)32 * 1024;
        vb0 += (size_t)32 * 512;
    }
    size_t base = ((size_t)(chunk * 64 + bh)) * 8320;   // 65*128
    #pragma unroll
    for (int i = 0; i < 2; ++i) {
        int d0 = w * 32 + i * 16 + (l >> 4) * 4;
        #pragma unroll
        for (int j = 0; j < 5; ++j) {
            int e = j * 16 + lr;
            if (j < 4 || e == 64)
                *(f32x4*)(PKV + base + (size_t)e * 128 + d0) = acc[i][j];
        }
    }
}

// reduce partials: kvT[bh][e=64][d=128], kmean[bh][128]
__global__ __launch_bounds__(256) void kvreduce_kernel(const float* __restrict__ PKV,
                                                       float* __restrict__ kvT,
                                                       float* __restrict__ kmean) {
    int gid = blockIdx.x * 256 + threadIdx.x;   // 0..532479 = 64*65*128
    const float inv_n = 1.0f / (float)NTOK;
    float s = 0.f;
    #pragma unroll
    for (int c = 0; c < 14; ++c) s += PKV[(size_t)c * 532480 + gid];
    s *= inv_n;
    int bh = gid / 8320;
    int r  = gid - bh * 8320;
    int e = r >> 7, d = r & 127;
    if (e < 64) kvT[(size_t)bh * 8192 + e * 128 + d] = s;
    else        kmean[bh * 128 + d] = s;
}

// ---------------- attention apply via MFMA: [64 tok][128] x [128][80] ----------------
__global__ __launch_bounds__(256) void attn_mfma_kernel(const float* __restrict__ Q,
                                                        const float* __restrict__ kvT,
                                                        const float* __restrict__ kmean,
                                                        const float* __restrict__ power,
                                                        float* __restrict__ ATT) {
    __shared__ ushort QF[64 * 128];
    __shared__ ushort BT[80 * 128];
    const int bh = blockIdx.x, tb = blockIdx.y;
    const int b = bh >> 3, head = bh & 7;
    const int t = threadIdx.x;
    const int w = t >> 6, l = t & 63;

    const int c = l;
    const float p = power[head * 64 + c];
    #pragma unroll
    for (int i = 0; i < 16; ++i) {
        int tok = i * 4 + w;
        float q = Q[((size_t)(b * NTOK + tb * 64 + tok)) * CDIM + head * 64 + c];
        float ax = fabsf(q);
        float tp = ax > 0.f ? __powf(ax, p) : 0.f;
        float qp = q > 0.f ? tp : 0.f;
        float qn = q < 0.f ? tp : 0.f;
        int sw = tok & 7;
        QF[tok * 128 + (((c >> 3) ^ sw) * 8) + (c & 7)]       = f2bf(qp);
        QF[tok * 128 + ((((c >> 3) + 8) ^ sw) * 8) + (c & 7)] = f2bf(qn);
    }
    #pragma unroll
    for (int i = 0; i < 5; ++i) {
        int qc = i * 256 + t;
        int row = qc >> 4, s = qc & 15;
        int ls = s ^ (row & 7);
        int d0 = ls * 8;
        short8 ov;
        if (row < 64) {
            int dsel = (row >= 32) ? (d0 ^ 64) : d0;
            const float* src = kvT + (size_t)bh * 8192 + row * 128 + dsel;
            #pragma unroll
            for (int e = 0; e < 8; ++e) ov[e] = (short)f2bf(src[e]);
        } else if (row == 64) {
            const float* src = kmean + bh * 128 + d0;
            #pragma unroll
            for (int e = 0; e < 8; ++e) ov[e] = (short)f2bf(src[e]);
        } else if (row == 65) {
            const float* src = kmean + bh * 128 + (d0 ^ 64);
            #pragma unroll
            for (int e = 0; e < 8; ++e) ov[e] = (short)f2bf(src[e]);
        } else {
            #pragma unroll
            for (int e = 0; e < 8; ++e) ov[e] = 0;
        }
        *(short8*)&BT[row * 128 + s * 8] = ov;
    }
    __syncthreads();

    f32x4 acc[5] = {};
    #pragma unroll
    for (int kk = 0; kk < 4; ++kk) {
        int sbase = kk * 4 + (l >> 4);
        int rowa = w * 16 + (l & 15);
        short8 af = *(const short8*)&QF[rowa * 128 + ((sbase ^ (rowa & 7)) * 8)];
        #pragma unroll
        for (int j = 0; j < 5; ++j) {
            int rowb = j * 16 + (l & 15);
            short8 bf = *(const short8*)&BT[rowb * 128 + ((sbase ^ (rowb & 7)) * 8)];
            acc[j] = __builtin_amdgcn_mfma_f32_16x16x32_bf16(af, bf, acc[j], 0, 0, 0);
        }
    }
    #pragma unroll
    for (int rr = 0; rr < 4; ++rr) {
        float ssim = __shfl(acc[4][rr], (l & 48));
        float sopp = __shfl(acc[4][rr], (l & 48) + 1);
        float zs = 1.f / (ssim + 1e-6f);
        float zo = 1.f / (sopp + 1e-6f);
        int tok = tb * 64 + w * 16 + (l >> 4) * 4 + rr;
        size_t base = ((size_t)(b * NTOK + tok)) * CDIM + head * 64;
        #pragma unroll
        for (int j = 0; j < 4; ++j) {
            int e = j * 16 + (l & 15);
            ATT[base + e] = acc[j][rr] * (j < 2 ? zs : zo);
        }
    }
}

// ---------------- v 5x5 depthwise conv (bf16 V) + gate ----------------
__global__ __launch_bounds__(256) void voutg2_kernel(const ushort* __restrict__ Vbf,
                                                     const float* __restrict__ ATT,
                                                     const float* __restrict__ G,
                                                     const float* __restrict__ dwc_w,
                                                     const float* __restrict__ dwc_b,
                                                     ushort* __restrict__ PRE) {
    const int t = threadIdx.x;
    const int c0 = t * 2;
    const int xpos = blockIdx.x;
    const int byc = blockIdx.y;
    const int b = byc >> 2, yc = byc & 3;
    const int y0 = yc * 14;
    const int dch = c0 & 63;

    float wgt[25][2];
    #pragma unroll
    for (int tap = 0; tap < 25; ++tap) {
        wgt[tap][0] = dwc_w[dch * 25 + tap];
        wgt[tap][1] = dwc_w[(dch + 1) * 25 + tap];
    }
    const float bias0 = dwc_b[dch], bias1 = dwc_b[dch + 1];
    const size_t base = (size_t)b * NTOK * CDIM + c0;

    float2 win[5][5];
    auto ldrow = [&](int yy, float2* dst) {
        #pragma unroll
        for (int dx = 0; dx < 5; ++dx) {
            int xx = xpos + dx - 2;
            bool ok = (yy >= 0 && yy < HW && xx >= 0 && xx < HW);
            if (ok) {
                ushort2 uv = *(const ushort2*)(Vbf + base + ((size_t)(yy * HW + xx) << 9));
                dst[dx] = make_float2(bf2f(uv.x), bf2f(uv.y));
            } else {
                dst[dx] = make_float2(0.f, 0.f);
            }
        }
    };
    ldrow(y0 - 2, win[0]);
    ldrow(y0 - 1, win[1]);
    ldrow(y0,     win[2]);
    ldrow(y0 + 1, win[3]);

    #pragma unroll
    for (int i = 0; i < 14; ++i) {
        int y = y0 + i;
        ldrow(y + 2, win[(i + 4) % 5]);
        float a0 = bias0, a1 = bias1;
        #pragma unroll
        for (int dy = 0; dy < 5; ++dy) {
            float2* row = win[(i + dy) % 5];
            #pragma unroll
            for (int dx = 0; dx < 5; ++dx) {
                a0 = fmaf(row[dx].x, wgt[dy * 5 + dx][0], a0);
                a1 = fmaf(row[dx].y, wgt[dy * 5 + dx][1], a1);
            }
        }
        size_t oidx = base + ((size_t)(y * HW + xpos) << 9);
        float2 att = *(const float2*)(ATT + oidx);
        float2 g   = *(const float2*)(G + oidx);
        ushort2 o;
        o.x = f2bf((att.x + a0) * g.x);
        o.y = f2bf((att.y + a1) * g.y);
        *(ushort2*)(PRE + oidx) = o;
    }
}

extern "C" void kernel_launch(void* const* d_in, const int* in_sizes, int n_in,
                              void* d_out, int out_size, void* d_ws, size_t ws_size,
                              hipStream_t stream) {
    const float* x      = (const float*)d_in[0];
    const float* qg_w   = (const float*)d_in[1];
    const float* kv_w   = (const float*)d_in[2];
    const float* proj_w = (const float*)d_in[3];
    const float* proj_b = (const float*)d_in[4];
    const float* dwc_w  = (const float*)d_in[5];
    const float* dwc_b  = (const float*)d_in[6];
    const float* power_p= (const float*)d_in[7];
    const float* scale_p= (const float*)d_in[8];
    const float* enh_w  = (const float*)d_in[9];
    const float* bn_g   = (const float*)d_in[10];
    const float* bn_b   = (const float*)d_in[11];
    const float* ew_p   = (const float*)d_in[12];
    const float* pos    = (const float*)d_in[13];

    const size_t NELEM = (size_t)MTOT * CDIM;   // 12,845,056
    float* ws    = (float*)d_ws;
    float* Qb    = ws;                  // fp32 Q
    float* Gb    = ws + NELEM;          // fp32 G
    float* Kb    = ws + 2 * NELEM;      // KFbf ushort [MTOT][1024] = 51.4MB; later PREbf
    float* Vb    = ws + 3 * NELEM;      // Vbf ushort [MTOT][512] (half used)
    float* QEb   = ws + 4 * NELEM;      // reused: Xbf, QE, PKV, ATT
    float* SMALL = ws + 5 * NELEM;
    float* ssum  = SMALL;               // 512
    float* ssq   = SMALL + 512;         // 512
    float* kmean = SMALL + 1024;        // 8192
    float* kvT   = SMALL + 9216;        // 524288 ([bh][e][d])
    float* invs  = SMALL + 533504;      // 512
    float* powr  = SMALL + 534016;      // 512
    float* achan = SMALL + 534528;      // 512
    float* bchan = SMALL + 535040;      // 512
    ushort* Wqg  = (ushort*)(SMALL + 535552);    // 524288 bf16
    ushort* Wkv  = (ushort*)(SMALL + 797696);    // 524288 bf16
    ushort* Wproj= (ushort*)(SMALL + 1059840);   // 262144 bf16

    ushort* Xbf  = (ushort*)QEb;        // x bf16 (dead after kv gemm; conv3 overwrites)
    ushort* KFbf = (ushort*)Kb;         // dead after kvred4
    ushort* Vbf  = (ushort*)Vb;
    float* PKV   = QEb;                 // 14*532480 floats (QE dead after qfin)
    float* ATTb  = QEb;                 // attn output (partials dead after kvreduce)
    ushort* PREbf= (ushort*)Kb;         // proj input bf16 (KFbf dead after kvred4)

    hipMemsetAsync(SMALL, 0, (size_t)1024 * sizeof(float), stream);

    prep_kernel<<<1, 512, 0, stream>>>(scale_p, power_p, invs, powr);

    cvt_bf16_kernel<<<12544, 256, 0, stream>>>(x, Xbf, 3211264);
    cvt_bf16_kernel<<<512, 256, 0, stream>>>(qg_w, Wqg, 131072);
    cvt_bf16_kernel<<<512, 256, 0, stream>>>(kv_w, Wkv, 131072);
    cvt_bf16_kernel<<<256, 256, 0, stream>>>(proj_w, Wproj, 65536);

    dim3 ggrid(196, 8);
    mgemm<0><<<ggrid, 256, 0, stream>>>(Xbf, Wqg, Qb, Gb, nullptr, nullptr, nullptr);
    mgemm<1><<<ggrid, 256, 0, stream>>>(Xbf, Wkv, KFbf, Vbf, pos, invs, powr);

    dim3 cgrid(56, 32);
    conv3s_kernel<<<cgrid, 256, 0, stream>>>(Qb, enh_w, QEb, ssum, ssq);
    bnprep_kernel<<<1, 512, 0, stream>>>(ssum, ssq, bn_g, bn_b, achan, bchan);
    qfin_kernel<<<50176, 256, 0, stream>>>(Qb, QEb, achan, bchan, invs, ew_p);

    kvred4_kernel<<<dim3(64, 14), 256, 0, stream>>>(KFbf, Vbf, PKV);
    kvreduce_kernel<<<2080, 256, 0, stream>>>(PKV, kvT, kmean);

    attn_mfma_kernel<<<dim3(64, 49), 256, 0, stream>>>(Qb, kvT, kmean, powr, ATTb);

    voutg2_kernel<<<cgrid, 256, 0, stream>>>(Vbf, ATTb, Gb, dwc_w, dwc_b, PREbf);

    dim3 pgrid(196, 4);
    mgemm<2><<<pgrid, 256, 0, stream>>>(PREbf, Wproj, (float*)d_out, nullptr, proj_b, nullptr, nullptr);
}